// Round 2
// baseline (2269.410 us; speedup 1.0000x reference)
//
#include <hip/hip_runtime.h>

// ---------------- degree / normalization ----------------

__global__ void init_deg_k(float* __restrict__ deg, int n) {
    int i = blockIdx.x * blockDim.x + threadIdx.x;
    if (i < n) deg[i] = 1.0f;  // self-loop
}

__global__ void deg_count_k(const int* __restrict__ dst, float* __restrict__ deg, int E) {
    int i = blockIdx.x * blockDim.x + threadIdx.x;
    if (i < E) atomicAdd(&deg[dst[i]], 1.0f);
}

__global__ void deg_rsqrt_k(float* __restrict__ deg, int n) {
    int i = blockIdx.x * blockDim.x + threadIdx.x;
    if (i < n) deg[i] = rsqrtf(deg[i]);  // deg >= 1 always (self-loops)
}

// ---------------- GEMM + scale-by-dis, dual write (hh and acc-init) ----------------
// hh[i][f] = (in[i]@W)[f] * dis[i];  acc initialized to hh (self-loop contribution)

template<int FIN, int FOUT>
__global__ __launch_bounds__(256) void gemm_scale_dual_k(
    const float* __restrict__ in, const float* __restrict__ W,
    const float* __restrict__ dis, float* __restrict__ hh,
    float* __restrict__ acc, int n)
{
    constexpr int ROWS = 16;
    __shared__ float Ws[FIN * FOUT];
    __shared__ float xs[ROWS * FIN];
    for (int i = threadIdx.x; i < FIN * FOUT; i += 256) Ws[i] = W[i];

    for (long long base = (long long)blockIdx.x * ROWS; base < n;
         base += (long long)gridDim.x * ROWS) {
        int cnt = (int)((n - base) < ROWS ? (n - base) : ROWS);
        __syncthreads();
        for (int i = threadIdx.x; i < cnt * FIN; i += 256)
            xs[i] = in[base * FIN + i];
        __syncthreads();
        for (int idx = threadIdx.x; idx < cnt * FOUT; idx += 256) {
            int r = idx / FOUT;
            int f = idx - r * FOUT;
            const float* xr = &xs[r * FIN];
            float a = 0.0f;
#pragma unroll 8
            for (int k = 0; k < FIN; ++k)
                a = fmaf(xr[k], Ws[k * FOUT + f], a);
            float v = a * dis[base + r];
            size_t o = (size_t)(base + r) * FOUT + f;
            hh[o]  = v;
            acc[o] = v;
        }
    }
}

// ---------------- edge scatter: acc[dst] += hh[src] ----------------

template<int F>
__global__ __launch_bounds__(256) void edge_scatter_k(
    const int* __restrict__ src, const int* __restrict__ dst,
    const float* __restrict__ hh, float* __restrict__ acc, int E)
{
    constexpr int EB = 64;  // edges staged per block
    __shared__ int s_src[EB], s_dst[EB];
    long long base = (long long)blockIdx.x * EB;
    if (base >= E) return;
    int cnt = (int)((E - base) < EB ? (E - base) : EB);
    if (threadIdx.x < (unsigned)cnt) {
        s_src[threadIdx.x] = src[base + threadIdx.x];
        s_dst[threadIdx.x] = dst[base + threadIdx.x];
    }
    __syncthreads();
    int total = cnt * F;
    for (int i = threadIdx.x; i < total; i += 256) {
        int e = i / F;
        int f = i - e * F;
        float v = hh[(size_t)s_src[e] * F + f];
        atomicAdd(&acc[(size_t)s_dst[e] * F + f], v);
    }
}

// ---------------- finalize: out = relu(dis[i]*acc + b[f]) in place ----------------

template<int F>
__global__ void finalize_k(const float* __restrict__ dis, const float* __restrict__ b,
                           float* __restrict__ acc, int n)
{
    long long idx = (long long)blockIdx.x * blockDim.x + threadIdx.x;
    if (idx < (long long)n * F) {
        int i = (int)(idx / F);
        int f = (int)(idx - (long long)i * F);
        float v = fmaf(dis[i], acc[idx], b[f]);
        acc[idx] = fmaxf(v, 0.0f);
    }
}

// ---------------- pooling ----------------

__global__ void zero_k(float* __restrict__ p, int n) {
    // grid-strided: must cover n fully regardless of grid size
    for (int i = blockIdx.x * blockDim.x + threadIdx.x; i < n;
         i += gridDim.x * blockDim.x)
        p[i] = 0.0f;
}

__global__ void pool_k(const float* __restrict__ h, const int* __restrict__ batch,
                       float* __restrict__ sums, float* __restrict__ cnt, int n)
{
    long long idx = (long long)blockIdx.x * blockDim.x + threadIdx.x;
    if (idx < (long long)n * 32) {
        int i = (int)(idx >> 5);
        int f = (int)(idx & 31);
        int g = batch[i];
        atomicAdd(&sums[g * 32 + f], h[idx]);
        if (f == 0) atomicAdd(&cnt[g], 1.0f);
    }
}

__global__ void head_k(const float* __restrict__ sums, const float* __restrict__ cnt,
                       const float* __restrict__ Wl, const float* __restrict__ bl,
                       float* __restrict__ out)
{
    int tid = threadIdx.x;
    if (tid < 128) {
        int g = tid >> 1;
        int o = tid & 1;
        float c = fmaxf(cnt[g], 1.0f);
        float a = 0.0f;
#pragma unroll
        for (int f = 0; f < 32; ++f)
            a += (sums[g * 32 + f] / c) * Wl[f * 2 + o];
        out[tid] = a + bl[o];
    }
}

// ---------------- launch ----------------

extern "C" void kernel_launch(void* const* d_in, const int* in_sizes, int n_in,
                              void* d_out, int out_size, void* d_ws, size_t ws_size,
                              hipStream_t stream)
{
    const float* x   = (const float*)d_in[0];
    const int*   ei  = (const int*)d_in[1];
    const int*   bat = (const int*)d_in[2];
    const float* W1  = (const float*)d_in[3];
    const float* b1  = (const float*)d_in[4];
    const float* W2  = (const float*)d_in[5];
    const float* b2  = (const float*)d_in[6];
    const float* W3  = (const float*)d_in[7];
    const float* b3  = (const float*)d_in[8];
    const float* Wl  = (const float*)d_in[9];
    const float* bl  = (const float*)d_in[10];

    const int N = in_sizes[0] / 128;
    const int E = in_sizes[1] / 2;
    const int* src = ei;
    const int* dst = ei + E;

    // workspace layout
    char* ws = (char*)d_ws;
    size_t off = 0;
    auto alloc = [&](size_t bytes) -> float* {
        float* p = (float*)(ws + off);
        off += (bytes + 255) & ~(size_t)255;
        return p;
    };
    float* dis = alloc((size_t)N * 4);
    float* A   = alloc((size_t)N * 84 * 4);  // hh buffer (max width)
    float* B   = alloc((size_t)N * 84 * 4);  // acc/out L1, reuse L3
    float* C   = alloc((size_t)N * 64 * 4);  // acc/out L2
    float* D   = alloc((size_t)(64 * 32 + 64) * 4);  // pool sums + counts

    dim3 blk(256);
    auto cdiv = [](long long a, long long b) { return (int)((a + b - 1) / b); };

    // normalization coefficients
    init_deg_k<<<cdiv(N, 256), blk, 0, stream>>>(dis, N);
    deg_count_k<<<cdiv(E, 256), blk, 0, stream>>>(dst, dis, E);
    deg_rsqrt_k<<<cdiv(N, 256), blk, 0, stream>>>(dis, N);

    int gemm_grid = cdiv(N, 16);
    if (gemm_grid > 4096) gemm_grid = 4096;

    // Layer 1: 128 -> 84
    gemm_scale_dual_k<128, 84><<<gemm_grid, blk, 0, stream>>>(x, W1, dis, A, B, N);
    edge_scatter_k<84><<<cdiv(E, 64), blk, 0, stream>>>(src, dst, A, B, E);
    finalize_k<84><<<cdiv((long long)N * 84, 256), blk, 0, stream>>>(dis, b1, B, N);

    // Layer 2: 84 -> 64
    gemm_scale_dual_k<84, 64><<<gemm_grid, blk, 0, stream>>>(B, W2, dis, A, C, N);
    edge_scatter_k<64><<<cdiv(E, 64), blk, 0, stream>>>(src, dst, A, C, E);
    finalize_k<64><<<cdiv((long long)N * 64, 256), blk, 0, stream>>>(dis, b2, C, N);

    // Layer 3: 64 -> 32
    gemm_scale_dual_k<64, 32><<<gemm_grid, blk, 0, stream>>>(C, W3, dis, A, B, N);
    edge_scatter_k<32><<<cdiv(E, 64), blk, 0, stream>>>(src, dst, A, B, E);
    finalize_k<32><<<cdiv((long long)N * 32, 256), blk, 0, stream>>>(dis, b3, B, N);

    // global mean pool + head
    zero_k<<<cdiv(64 * 32 + 64, 256), blk, 0, stream>>>(D, 64 * 32 + 64);
    pool_k<<<cdiv((long long)N * 32, 256), blk, 0, stream>>>(B, bat, D, D + 64 * 32, N);
    head_k<<<1, 128, 0, stream>>>(D, D + 64 * 32, Wl, bl, (float*)d_out);
}

// Round 3
// 1434.964 us; speedup vs baseline: 1.5815x; 1.5815x over previous
//
#include <hip/hip_runtime.h>

// ---------------- degree / normalization ----------------

__global__ void init_deg_k(float* __restrict__ deg, int n) {
    int i = blockIdx.x * blockDim.x + threadIdx.x;
    if (i < n) deg[i] = 1.0f;  // self-loop
}

__global__ void deg_count_k(const int* __restrict__ dst, float* __restrict__ deg, int E) {
    int i = blockIdx.x * blockDim.x + threadIdx.x;
    if (i < E) atomicAdd(&deg[dst[i]], 1.0f);
}

__global__ void deg_rsqrt_k(float* __restrict__ deg, int n) {
    int i = blockIdx.x * blockDim.x + threadIdx.x;
    if (i < n) deg[i] = rsqrtf(deg[i]);  // deg >= 1 always (self-loops)
}

// ---------------- GEMM + scale-by-dis, dual write (hh and acc-init) ----------------

template<int FIN, int FOUT>
__global__ __launch_bounds__(256) void gemm_scale_dual_k(
    const float* __restrict__ in, const float* __restrict__ W,
    const float* __restrict__ dis, float* __restrict__ hh,
    float* __restrict__ acc, int n)
{
    constexpr int ROWS = 16;
    __shared__ float Ws[FIN * FOUT];
    __shared__ float xs[ROWS * FIN];
    for (int i = threadIdx.x; i < FIN * FOUT; i += 256) Ws[i] = W[i];

    for (long long base = (long long)blockIdx.x * ROWS; base < n;
         base += (long long)gridDim.x * ROWS) {
        int cnt = (int)((n - base) < ROWS ? (n - base) : ROWS);
        __syncthreads();
        for (int i = threadIdx.x; i < cnt * FIN; i += 256)
            xs[i] = in[base * FIN + i];
        __syncthreads();
        for (int idx = threadIdx.x; idx < cnt * FOUT; idx += 256) {
            int r = idx / FOUT;
            int f = idx - r * FOUT;
            const float* xr = &xs[r * FIN];
            float a = 0.0f;
#pragma unroll 8
            for (int k = 0; k < FIN; ++k)
                a = fmaf(xr[k], Ws[k * FOUT + f], a);
            float v = a * dis[base + r];
            size_t o = (size_t)(base + r) * FOUT + f;
            hh[o]  = v;
            acc[o] = v;
        }
    }
}

// ---------------- edge scatter: acc[dst] += hh[src] ----------------

template<int F>
__global__ __launch_bounds__(256) void edge_scatter_k(
    const int* __restrict__ src, const int* __restrict__ dst,
    const float* __restrict__ hh, float* __restrict__ acc, int E)
{
    constexpr int EB = 64;
    __shared__ int s_src[EB], s_dst[EB];
    long long base = (long long)blockIdx.x * EB;
    if (base >= E) return;
    int cnt = (int)((E - base) < EB ? (E - base) : EB);
    if (threadIdx.x < (unsigned)cnt) {
        s_src[threadIdx.x] = src[base + threadIdx.x];
        s_dst[threadIdx.x] = dst[base + threadIdx.x];
    }
    __syncthreads();
    int total = cnt * F;
    for (int i = threadIdx.x; i < total; i += 256) {
        int e = i / F;
        int f = i - e * F;
        float v = hh[(size_t)s_src[e] * F + f];
        atomicAdd(&acc[(size_t)s_dst[e] * F + f], v);
    }
}

// ---------------- finalize: out = relu(dis[i]*acc + b[f]) in place ----------------

template<int F>
__global__ void finalize_k(const float* __restrict__ dis, const float* __restrict__ b,
                           float* __restrict__ acc, int n)
{
    long long idx = (long long)blockIdx.x * blockDim.x + threadIdx.x;
    if (idx < (long long)n * F) {
        int i = (int)(idx / F);
        int f = (int)(idx - (long long)i * F);
        float v = fmaf(dis[i], acc[idx], b[f]);
        acc[idx] = fmaxf(v, 0.0f);
    }
}

// ---------------- pooling ----------------

__global__ void zero_k(float* __restrict__ p, int n) {
    for (int i = blockIdx.x * blockDim.x + threadIdx.x; i < n;
         i += gridDim.x * blockDim.x)
        p[i] = 0.0f;
}

// per-block LDS reduction over a 1024-node chunk, then sparse flush.
// batch is sorted -> a block spans ~1-2 graphs -> ~100 nonzero flush entries.
__global__ __launch_bounds__(256) void pool2_k(
    const float* __restrict__ h, const int* __restrict__ batch,
    float* __restrict__ sums, float* __restrict__ cnt, int n)
{
    constexpr int CHUNK = 1024;
    __shared__ float s[64 * 32];
    __shared__ float sc[64];
    for (int i = threadIdx.x; i < 64 * 32; i += 256) s[i] = 0.0f;
    if (threadIdx.x < 64) sc[threadIdx.x] = 0.0f;
    __syncthreads();

    long long start = (long long)blockIdx.x * CHUNK;
    long long end = start + CHUNK < n ? start + CHUNK : n;
    int total = (int)(end - start) * 32;
    for (int i = threadIdx.x; i < total; i += 256) {
        int r = i >> 5;
        int f = i & 31;
        int node = (int)start + r;
        int g = batch[node];
        atomicAdd(&s[g * 32 + f], h[(size_t)node * 32 + f]);
        if (f == 0) atomicAdd(&sc[g], 1.0f);
    }
    __syncthreads();
    for (int i = threadIdx.x; i < 64 * 32; i += 256) {
        float v = s[i];
        if (v != 0.0f) atomicAdd(&sums[i], v);
    }
    if (threadIdx.x < 64) {
        float v = sc[threadIdx.x];
        if (v != 0.0f) atomicAdd(&cnt[threadIdx.x], v);
    }
}

__global__ void head_k(const float* __restrict__ sums, const float* __restrict__ cnt,
                       const float* __restrict__ Wl, const float* __restrict__ bl,
                       float* __restrict__ out)
{
    int tid = threadIdx.x;
    if (tid < 128) {
        int g = tid >> 1;
        int o = tid & 1;
        float c = fmaxf(cnt[g], 1.0f);
        float a = 0.0f;
#pragma unroll
        for (int f = 0; f < 32; ++f)
            a += (sums[g * 32 + f] / c) * Wl[f * 2 + o];
        out[tid] = a + bl[o];
    }
}

// ---------------- launch ----------------

extern "C" void kernel_launch(void* const* d_in, const int* in_sizes, int n_in,
                              void* d_out, int out_size, void* d_ws, size_t ws_size,
                              hipStream_t stream)
{
    const float* x   = (const float*)d_in[0];
    const int*   ei  = (const int*)d_in[1];
    const int*   bat = (const int*)d_in[2];
    const float* W1  = (const float*)d_in[3];
    const float* b1  = (const float*)d_in[4];
    const float* W2  = (const float*)d_in[5];
    const float* b2  = (const float*)d_in[6];
    const float* W3  = (const float*)d_in[7];
    const float* b3  = (const float*)d_in[8];
    const float* Wl  = (const float*)d_in[9];
    const float* bl  = (const float*)d_in[10];

    const int N = in_sizes[0] / 128;
    const int E = in_sizes[1] / 2;
    const int* src = ei;
    const int* dst = ei + E;

    char* ws = (char*)d_ws;
    size_t off = 0;
    auto alloc = [&](size_t bytes) -> float* {
        float* p = (float*)(ws + off);
        off += (bytes + 255) & ~(size_t)255;
        return p;
    };
    float* dis = alloc((size_t)N * 4);
    float* A   = alloc((size_t)N * 84 * 4);
    float* B   = alloc((size_t)N * 84 * 4);
    float* C   = alloc((size_t)N * 64 * 4);
    float* D   = alloc((size_t)(64 * 32 + 64) * 4);

    dim3 blk(256);
    auto cdiv = [](long long a, long long b) { return (int)((a + b - 1) / b); };

    init_deg_k<<<cdiv(N, 256), blk, 0, stream>>>(dis, N);
    deg_count_k<<<cdiv(E, 256), blk, 0, stream>>>(dst, dis, E);
    deg_rsqrt_k<<<cdiv(N, 256), blk, 0, stream>>>(dis, N);

    int gemm_grid = cdiv(N, 16);
    if (gemm_grid > 4096) gemm_grid = 4096;

    // Layer 1: 128 -> 84
    gemm_scale_dual_k<128, 84><<<gemm_grid, blk, 0, stream>>>(x, W1, dis, A, B, N);
    edge_scatter_k<84><<<cdiv(E, 64), blk, 0, stream>>>(src, dst, A, B, E);
    finalize_k<84><<<cdiv((long long)N * 84, 256), blk, 0, stream>>>(dis, b1, B, N);

    // Layer 2: 84 -> 64
    gemm_scale_dual_k<84, 64><<<gemm_grid, blk, 0, stream>>>(B, W2, dis, A, C, N);
    edge_scatter_k<64><<<cdiv(E, 64), blk, 0, stream>>>(src, dst, A, C, E);
    finalize_k<64><<<cdiv((long long)N * 64, 256), blk, 0, stream>>>(dis, b2, C, N);

    // Layer 3: 64 -> 32
    gemm_scale_dual_k<64, 32><<<gemm_grid, blk, 0, stream>>>(C, W3, dis, A, B, N);
    edge_scatter_k<32><<<cdiv(E, 64), blk, 0, stream>>>(src, dst, A, B, E);
    finalize_k<32><<<cdiv((long long)N * 32, 256), blk, 0, stream>>>(dis, b3, B, N);

    // global mean pool + head
    zero_k<<<cdiv(64 * 32 + 64, 256), blk, 0, stream>>>(D, 64 * 32 + 64);
    pool2_k<<<cdiv(N, 1024), blk, 0, stream>>>(B, bat, D, D + 64 * 32, N);
    head_k<<<1, 128, 0, stream>>>(D, D + 64 * 32, Wl, bl, (float*)d_out);
}

// Round 4
// 758.374 us; speedup vs baseline: 2.9925x; 1.8922x over previous
//
#include <hip/hip_runtime.h>

// ---------------- utility ----------------

__global__ void zero_int_k(int* __restrict__ p, int n) {
    for (int i = blockIdx.x * blockDim.x + threadIdx.x; i < n;
         i += gridDim.x * blockDim.x)
        p[i] = 0;
}

__global__ void zero_k(float* __restrict__ p, int n) {
    for (int i = blockIdx.x * blockDim.x + threadIdx.x; i < n;
         i += gridDim.x * blockDim.x)
        p[i] = 0.0f;
}

// ---------------- CSR build ----------------

__global__ void hist_k(const int* __restrict__ dst, int* __restrict__ cnt, int E) {
    int i = blockIdx.x * blockDim.x + threadIdx.x;
    if (i < E) atomicAdd(&cnt[dst[i]], 1);
}

__global__ void dis_k(const int* __restrict__ cnt, float* __restrict__ dis, int n) {
    int i = blockIdx.x * blockDim.x + threadIdx.x;
    if (i < n) dis[i] = rsqrtf(1.0f + (float)cnt[i]);  // +1 self-loop
}

// exclusive scan, 2048 elements per block (256 thr x 8)
__global__ __launch_bounds__(256) void scan_block_k(
    const int* __restrict__ in, int* __restrict__ out,
    int* __restrict__ bsum, int n)
{
    __shared__ int ts[256];
    int base = blockIdx.x * 2048;
    int i0 = base + threadIdx.x * 8;
    int vals[8];
    int s = 0;
#pragma unroll
    for (int j = 0; j < 8; ++j) {
        int v = (i0 + j) < n ? in[i0 + j] : 0;
        vals[j] = v; s += v;
    }
    ts[threadIdx.x] = s;
    __syncthreads();
    for (int d = 1; d < 256; d <<= 1) {
        int t = (threadIdx.x >= (unsigned)d) ? ts[threadIdx.x - d] : 0;
        __syncthreads();
        ts[threadIdx.x] += t;
        __syncthreads();
    }
    int run = ts[threadIdx.x] - s;  // exclusive prefix of this thread
    if (threadIdx.x == 255) bsum[blockIdx.x] = ts[255];
#pragma unroll
    for (int j = 0; j < 8; ++j) {
        if (i0 + j < n) out[i0 + j] = run;
        run += vals[j];
    }
}

__global__ void scan_partials_k(int* __restrict__ bsum, int nb) {
    if (threadIdx.x == 0 && blockIdx.x == 0) {
        int run = 0;
        for (int i = 0; i < nb; ++i) { int t = bsum[i]; bsum[i] = run; run += t; }
    }
}

__global__ void scan_add_k(int* __restrict__ rp, const int* __restrict__ bsum,
                           int* __restrict__ cursor, int n, int E)
{
    int i = blockIdx.x * blockDim.x + threadIdx.x;
    if (i < n) {
        int v = rp[i] + bsum[i >> 11];
        rp[i] = v;
        cursor[i] = v;
    }
    if (i == 0) rp[n] = E;
}

__global__ void csr_fill_k(const int* __restrict__ src, const int* __restrict__ dst,
                           int* __restrict__ cursor, int* __restrict__ csr, int E)
{
    int i = blockIdx.x * blockDim.x + threadIdx.x;
    if (i < E) {
        int pos = atomicAdd(&cursor[dst[i]], 1);
        csr[pos] = src[i];
    }
}

// ---------------- GEMM + scale-by-dis: hh[i][f] = (in[i]@W)[f] * dis[i] ----------------

template<int FIN, int FOUT>
__global__ __launch_bounds__(256) void gemm_scale_k(
    const float* __restrict__ in, const float* __restrict__ W,
    const float* __restrict__ dis, float* __restrict__ hh, int n)
{
    constexpr int ROWS = 16;
    __shared__ float Ws[FIN * FOUT];
    __shared__ float xs[ROWS * FIN];
    for (int i = threadIdx.x; i < FIN * FOUT; i += 256) Ws[i] = W[i];

    for (long long base = (long long)blockIdx.x * ROWS; base < n;
         base += (long long)gridDim.x * ROWS) {
        int cnt = (int)((n - base) < ROWS ? (n - base) : ROWS);
        __syncthreads();
        for (int i = threadIdx.x; i < cnt * FIN; i += 256)
            xs[i] = in[base * FIN + i];
        __syncthreads();
        for (int idx = threadIdx.x; idx < cnt * FOUT; idx += 256) {
            int r = idx / FOUT;
            int f = idx - r * FOUT;
            const float* xr = &xs[r * FIN];
            float a = 0.0f;
#pragma unroll 8
            for (int k = 0; k < FIN; ++k)
                a = fmaf(xr[k], Ws[k * FOUT + f], a);
            hh[(size_t)(base + r) * FOUT + f] = a * dis[base + r];
        }
    }
}

// ---------------- CSR aggregate + bias + relu (fused finalize) ----------------
// out[d][f] = relu(dis[d] * (hh[d][f] + sum_{e in in(d)} hh[src[e]][f]) + b[f])

template<int F>
__global__ __launch_bounds__(256) void aggregate_k(
    const float* __restrict__ hh, const int* __restrict__ row_ptr,
    const int* __restrict__ csr, const float* __restrict__ dis,
    const float* __restrict__ b, float* __restrict__ out, int n)
{
    long long idx = (long long)blockIdx.x * 256 + threadIdx.x;
    if (idx >= (long long)n * F) return;
    int node = (int)(idx / F);
    int f = (int)(idx - (long long)node * F);
    float a = hh[idx];  // self-loop term
    int e = row_ptr[node];
    int e1 = row_ptr[node + 1];
    for (; e + 1 < e1; e += 2) {
        int s0 = csr[e], s1 = csr[e + 1];
        float v0 = hh[(size_t)s0 * F + f];
        float v1 = hh[(size_t)s1 * F + f];
        a += v0; a += v1;
    }
    if (e < e1) a += hh[(size_t)csr[e] * F + f];
    out[idx] = fmaxf(fmaf(dis[node], a, b[f]), 0.0f);
}

// ---------------- pooling ----------------

__global__ __launch_bounds__(256) void pool2_k(
    const float* __restrict__ h, const int* __restrict__ batch,
    float* __restrict__ sums, float* __restrict__ cnt, int n)
{
    constexpr int CHUNK = 1024;
    __shared__ float s[64 * 32];
    __shared__ float sc[64];
    for (int i = threadIdx.x; i < 64 * 32; i += 256) s[i] = 0.0f;
    if (threadIdx.x < 64) sc[threadIdx.x] = 0.0f;
    __syncthreads();

    long long start = (long long)blockIdx.x * CHUNK;
    long long end = start + CHUNK < n ? start + CHUNK : n;
    int total = (int)(end - start) * 32;
    for (int i = threadIdx.x; i < total; i += 256) {
        int r = i >> 5;
        int f = i & 31;
        int node = (int)start + r;
        int g = batch[node];
        atomicAdd(&s[g * 32 + f], h[(size_t)node * 32 + f]);
        if (f == 0) atomicAdd(&sc[g], 1.0f);
    }
    __syncthreads();
    for (int i = threadIdx.x; i < 64 * 32; i += 256) {
        float v = s[i];
        if (v != 0.0f) atomicAdd(&sums[i], v);
    }
    if (threadIdx.x < 64) {
        float v = sc[threadIdx.x];
        if (v != 0.0f) atomicAdd(&cnt[threadIdx.x], v);
    }
}

__global__ void head_k(const float* __restrict__ sums, const float* __restrict__ cnt,
                       const float* __restrict__ Wl, const float* __restrict__ bl,
                       float* __restrict__ out)
{
    int tid = threadIdx.x;
    if (tid < 128) {
        int g = tid >> 1;
        int o = tid & 1;
        float c = fmaxf(cnt[g], 1.0f);
        float a = 0.0f;
#pragma unroll
        for (int f = 0; f < 32; ++f)
            a += (sums[g * 32 + f] / c) * Wl[f * 2 + o];
        out[tid] = a + bl[o];
    }
}

// ---------------- launch ----------------

extern "C" void kernel_launch(void* const* d_in, const int* in_sizes, int n_in,
                              void* d_out, int out_size, void* d_ws, size_t ws_size,
                              hipStream_t stream)
{
    const float* x   = (const float*)d_in[0];
    const int*   ei  = (const int*)d_in[1];
    const int*   bat = (const int*)d_in[2];
    const float* W1  = (const float*)d_in[3];
    const float* b1  = (const float*)d_in[4];
    const float* W2  = (const float*)d_in[5];
    const float* b2  = (const float*)d_in[6];
    const float* W3  = (const float*)d_in[7];
    const float* b3  = (const float*)d_in[8];
    const float* Wl  = (const float*)d_in[9];
    const float* bl  = (const float*)d_in[10];

    const int N = in_sizes[0] / 128;
    const int E = in_sizes[1] / 2;
    const int* src = ei;
    const int* dst = ei + E;

    char* ws = (char*)d_ws;
    size_t off = 0;
    auto alloc = [&](size_t bytes) -> char* {
        char* p = ws + off;
        off += (bytes + 255) & ~(size_t)255;
        return p;
    };
    float* dis     = (float*)alloc((size_t)N * 4);
    int*   cnt     = (int*)  alloc((size_t)N * 4);      // histogram, later reused as cursor
    int*   row_ptr = (int*)  alloc((size_t)(N + 1) * 4);
    int*   bsum    = (int*)  alloc(256 * 4);
    int*   csr     = (int*)  alloc((size_t)E * 4);
    float* A       = (float*)alloc((size_t)N * 84 * 4); // hh buffer
    float* B       = (float*)alloc((size_t)N * 84 * 4); // layer outputs 1,3
    float* C       = (float*)alloc((size_t)N * 64 * 4); // layer output 2
    float* D       = (float*)alloc((size_t)(64 * 32 + 64) * 4);

    dim3 blk(256);
    auto cdiv = [](long long a, long long b) { return (int)((a + b - 1) / b); };

    // ---- CSR build + normalization ----
    zero_int_k<<<cdiv(N, 256), blk, 0, stream>>>(cnt, N);
    hist_k<<<cdiv(E, 256), blk, 0, stream>>>(dst, cnt, E);
    dis_k<<<cdiv(N, 256), blk, 0, stream>>>(cnt, dis, N);
    int nb_scan = cdiv(N, 2048);
    scan_block_k<<<nb_scan, blk, 0, stream>>>(cnt, row_ptr, bsum, N);
    scan_partials_k<<<1, 64, 0, stream>>>(bsum, nb_scan);
    scan_add_k<<<cdiv(N, 256), blk, 0, stream>>>(row_ptr, bsum, cnt /*cursor*/, N, E);
    csr_fill_k<<<cdiv(E, 256), blk, 0, stream>>>(src, dst, cnt /*cursor*/, csr, E);

    int gemm_grid = cdiv(N, 16);
    if (gemm_grid > 4096) gemm_grid = 4096;

    // Layer 1: 128 -> 84
    gemm_scale_k<128, 84><<<gemm_grid, blk, 0, stream>>>(x, W1, dis, A, N);
    aggregate_k<84><<<cdiv((long long)N * 84, 256), blk, 0, stream>>>(A, row_ptr, csr, dis, b1, B, N);

    // Layer 2: 84 -> 64
    gemm_scale_k<84, 64><<<gemm_grid, blk, 0, stream>>>(B, W2, dis, A, N);
    aggregate_k<64><<<cdiv((long long)N * 64, 256), blk, 0, stream>>>(A, row_ptr, csr, dis, b2, C, N);

    // Layer 3: 64 -> 32
    gemm_scale_k<64, 32><<<gemm_grid, blk, 0, stream>>>(C, W3, dis, A, N);
    aggregate_k<32><<<cdiv((long long)N * 32, 256), blk, 0, stream>>>(A, row_ptr, csr, dis, b3, B, N);

    // global mean pool + head
    zero_k<<<cdiv(64 * 32 + 64, 256), blk, 0, stream>>>(D, 64 * 32 + 64);
    pool2_k<<<cdiv(N, 1024), blk, 0, stream>>>(B, bat, D, D + 64 * 32, N);
    head_k<<<1, 128, 0, stream>>>(D, D + 64 * 32, Wl, bl, (float*)d_out);
}

// Round 5
// 635.767 us; speedup vs baseline: 3.5696x; 1.1928x over previous
//
#include <hip/hip_runtime.h>

// ---------------- utility ----------------

__global__ void zero_int_k(int* __restrict__ p, int n) {
    for (int i = blockIdx.x * blockDim.x + threadIdx.x; i < n;
         i += gridDim.x * blockDim.x)
        p[i] = 0;
}

__global__ void zero_k(float* __restrict__ p, int n) {
    for (int i = blockIdx.x * blockDim.x + threadIdx.x; i < n;
         i += gridDim.x * blockDim.x)
        p[i] = 0.0f;
}

// ---------------- CSR build ----------------

__global__ void hist_k(const int* __restrict__ dst, int* __restrict__ cnt, int E) {
    int i = blockIdx.x * blockDim.x + threadIdx.x;
    if (i < E) atomicAdd(&cnt[dst[i]], 1);
}

__global__ void dis_k(const int* __restrict__ cnt, float* __restrict__ dis, int n) {
    int i = blockIdx.x * blockDim.x + threadIdx.x;
    if (i < n) dis[i] = rsqrtf(1.0f + (float)cnt[i]);  // +1 self-loop
}

// exclusive scan, 2048 elements per block (256 thr x 8)
__global__ __launch_bounds__(256) void scan_block_k(
    const int* __restrict__ in, int* __restrict__ out,
    int* __restrict__ bsum, int n)
{
    __shared__ int ts[256];
    int base = blockIdx.x * 2048;
    int i0 = base + threadIdx.x * 8;
    int vals[8];
    int s = 0;
#pragma unroll
    for (int j = 0; j < 8; ++j) {
        int v = (i0 + j) < n ? in[i0 + j] : 0;
        vals[j] = v; s += v;
    }
    ts[threadIdx.x] = s;
    __syncthreads();
    for (int d = 1; d < 256; d <<= 1) {
        int t = (threadIdx.x >= (unsigned)d) ? ts[threadIdx.x - d] : 0;
        __syncthreads();
        ts[threadIdx.x] += t;
        __syncthreads();
    }
    int run = ts[threadIdx.x] - s;  // exclusive prefix of this thread
    if (threadIdx.x == 255) bsum[blockIdx.x] = ts[255];
#pragma unroll
    for (int j = 0; j < 8; ++j) {
        if (i0 + j < n) out[i0 + j] = run;
        run += vals[j];
    }
}

__global__ void scan_partials_k(int* __restrict__ bsum, int nb) {
    if (threadIdx.x == 0 && blockIdx.x == 0) {
        int run = 0;
        for (int i = 0; i < nb; ++i) { int t = bsum[i]; bsum[i] = run; run += t; }
    }
}

__global__ void scan_add_k(int* __restrict__ rp, const int* __restrict__ bsum,
                           int* __restrict__ cursor, int n, int E)
{
    int i = blockIdx.x * blockDim.x + threadIdx.x;
    if (i < n) {
        int v = rp[i] + bsum[i >> 11];
        rp[i] = v;
        cursor[i] = v;
    }
    if (i == 0) rp[n] = E;
}

__global__ void csr_fill_k(const int* __restrict__ src, const int* __restrict__ dst,
                           int* __restrict__ cursor, int* __restrict__ csr, int E)
{
    int i = blockIdx.x * blockDim.x + threadIdx.x;
    if (i < E) {
        int pos = atomicAdd(&cursor[dst[i]], 1);
        csr[pos] = src[i];
    }
}

// ---------------- GEMM v2: 4x4 register-blocked, transposed-x LDS ----------------
// hh[i][f] = (in[i]@W)[f] * dis[i]
// Per thread: 4 rows x 4 cols; per k: 1 float4 of x + 1 float4 of W -> 16 FMA.
// x staged transposed (xs[k][r], stride SR) with XOR swizzle on 4-row groups
// by (k>>2)&3 to break the strided-write bank conflict (4*SR % 32 in {0,16}).

template<int FIN, int FOUT, int TILE_R>
__global__ __launch_bounds__(256) void gemm_scale_v2(
    const float* __restrict__ in, const float* __restrict__ W,
    const float* __restrict__ dis, float* __restrict__ hh, int n)
{
    constexpr int RG = TILE_R / 4;
    constexpr int CG = FOUT / 4;
    constexpr int NMT = RG * CG;
    static_assert(NMT <= 256, "tile too big");
    static_assert((RG & 3) == 0, "swizzle needs RG multiple of 4");
    constexpr int SR = TILE_R + 4;  // dword stride, multiple of 4 (float4 alignment)
    __shared__ float Ws[FIN * FOUT];
    __shared__ float xs[FIN * SR];

    for (int i = threadIdx.x; i < FIN * FOUT; i += 256) Ws[i] = W[i];

    const int tid = threadIdx.x;
    const int rg = tid / CG;
    const int cg = tid - rg * CG;
    const bool active = tid < NMT;

    for (long long base = (long long)blockIdx.x * TILE_R; base < n;
         base += (long long)gridDim.x * TILE_R) {
        const int cnt = (int)((n - base) < TILE_R ? (n - base) : TILE_R);
        __syncthreads();
        // stage transposed: xs[k*SR + ((r>>2 ^ (k>>2)&3)<<2) + (r&3)]
        for (int i = tid; i < TILE_R * (FIN / 4); i += 256) {
            int r  = i / (FIN / 4);
            int c4 = i - r * (FIN / 4);
            float4 v;
            if (r < cnt)
                v = *reinterpret_cast<const float4*>(&in[(base + r) * FIN + c4 * 4]);
            else
                v = make_float4(0.f, 0.f, 0.f, 0.f);
            int gph = (((r >> 2) ^ (c4 & 3)) << 2) + (r & 3);
            float* p = &xs[(c4 * 4) * SR + gph];
            p[0]      = v.x;
            p[SR]     = v.y;
            p[2 * SR] = v.z;
            p[3 * SR] = v.w;
        }
        __syncthreads();
        if (active) {
            float acc[4][4];
#pragma unroll
            for (int i = 0; i < 4; ++i)
#pragma unroll
                for (int j = 0; j < 4; ++j) acc[i][j] = 0.f;

#pragma unroll 8
            for (int k = 0; k < FIN; ++k) {
                float4 xa = *reinterpret_cast<const float4*>(
                    &xs[k * SR + ((rg ^ ((k >> 2) & 3)) << 2)]);
                float4 wb = *reinterpret_cast<const float4*>(&Ws[k * FOUT + cg * 4]);
                acc[0][0] = fmaf(xa.x, wb.x, acc[0][0]);
                acc[0][1] = fmaf(xa.x, wb.y, acc[0][1]);
                acc[0][2] = fmaf(xa.x, wb.z, acc[0][2]);
                acc[0][3] = fmaf(xa.x, wb.w, acc[0][3]);
                acc[1][0] = fmaf(xa.y, wb.x, acc[1][0]);
                acc[1][1] = fmaf(xa.y, wb.y, acc[1][1]);
                acc[1][2] = fmaf(xa.y, wb.z, acc[1][2]);
                acc[1][3] = fmaf(xa.y, wb.w, acc[1][3]);
                acc[2][0] = fmaf(xa.z, wb.x, acc[2][0]);
                acc[2][1] = fmaf(xa.z, wb.y, acc[2][1]);
                acc[2][2] = fmaf(xa.z, wb.z, acc[2][2]);
                acc[2][3] = fmaf(xa.z, wb.w, acc[2][3]);
                acc[3][0] = fmaf(xa.w, wb.x, acc[3][0]);
                acc[3][1] = fmaf(xa.w, wb.y, acc[3][1]);
                acc[3][2] = fmaf(xa.w, wb.z, acc[3][2]);
                acc[3][3] = fmaf(xa.w, wb.w, acc[3][3]);
            }
#pragma unroll
            for (int i = 0; i < 4; ++i) {
                int r = rg * 4 + i;
                if (r < cnt) {
                    float d = dis[base + r];
                    float4 o;
                    o.x = acc[i][0] * d;
                    o.y = acc[i][1] * d;
                    o.z = acc[i][2] * d;
                    o.w = acc[i][3] * d;
                    *reinterpret_cast<float4*>(
                        &hh[(size_t)(base + r) * FOUT + cg * 4]) = o;
                }
            }
        }
    }
}

// ---------------- CSR aggregate + bias + relu (fused finalize) ----------------

template<int F>
__global__ __launch_bounds__(256) void aggregate_k(
    const float* __restrict__ hh, const int* __restrict__ row_ptr,
    const int* __restrict__ csr, const float* __restrict__ dis,
    const float* __restrict__ b, float* __restrict__ out, int n)
{
    long long idx = (long long)blockIdx.x * 256 + threadIdx.x;
    if (idx >= (long long)n * F) return;
    int node = (int)(idx / F);
    int f = (int)(idx - (long long)node * F);
    float a = hh[idx];  // self-loop term
    int e = row_ptr[node];
    int e1 = row_ptr[node + 1];
    for (; e + 1 < e1; e += 2) {
        int s0 = csr[e], s1 = csr[e + 1];
        float v0 = hh[(size_t)s0 * F + f];
        float v1 = hh[(size_t)s1 * F + f];
        a += v0; a += v1;
    }
    if (e < e1) a += hh[(size_t)csr[e] * F + f];
    out[idx] = fmaxf(fmaf(dis[node], a, b[f]), 0.0f);
}

// ---------------- pooling ----------------

__global__ __launch_bounds__(256) void pool2_k(
    const float* __restrict__ h, const int* __restrict__ batch,
    float* __restrict__ sums, float* __restrict__ cnt, int n)
{
    constexpr int CHUNK = 1024;
    __shared__ float s[64 * 32];
    __shared__ float sc[64];
    for (int i = threadIdx.x; i < 64 * 32; i += 256) s[i] = 0.0f;
    if (threadIdx.x < 64) sc[threadIdx.x] = 0.0f;
    __syncthreads();

    long long start = (long long)blockIdx.x * CHUNK;
    long long end = start + CHUNK < n ? start + CHUNK : n;
    int total = (int)(end - start) * 32;
    for (int i = threadIdx.x; i < total; i += 256) {
        int r = i >> 5;
        int f = i & 31;
        int node = (int)start + r;
        int g = batch[node];
        atomicAdd(&s[g * 32 + f], h[(size_t)node * 32 + f]);
        if (f == 0) atomicAdd(&sc[g], 1.0f);
    }
    __syncthreads();
    for (int i = threadIdx.x; i < 64 * 32; i += 256) {
        float v = s[i];
        if (v != 0.0f) atomicAdd(&sums[i], v);
    }
    if (threadIdx.x < 64) {
        float v = sc[threadIdx.x];
        if (v != 0.0f) atomicAdd(&cnt[threadIdx.x], v);
    }
}

__global__ void head_k(const float* __restrict__ sums, const float* __restrict__ cnt,
                       const float* __restrict__ Wl, const float* __restrict__ bl,
                       float* __restrict__ out)
{
    int tid = threadIdx.x;
    if (tid < 128) {
        int g = tid >> 1;
        int o = tid & 1;
        float c = fmaxf(cnt[g], 1.0f);
        float a = 0.0f;
#pragma unroll
        for (int f = 0; f < 32; ++f)
            a += (sums[g * 32 + f] / c) * Wl[f * 2 + o];
        out[tid] = a + bl[o];
    }
}

// ---------------- launch ----------------

extern "C" void kernel_launch(void* const* d_in, const int* in_sizes, int n_in,
                              void* d_out, int out_size, void* d_ws, size_t ws_size,
                              hipStream_t stream)
{
    const float* x   = (const float*)d_in[0];
    const int*   ei  = (const int*)d_in[1];
    const int*   bat = (const int*)d_in[2];
    const float* W1  = (const float*)d_in[3];
    const float* b1  = (const float*)d_in[4];
    const float* W2  = (const float*)d_in[5];
    const float* b2  = (const float*)d_in[6];
    const float* W3  = (const float*)d_in[7];
    const float* b3  = (const float*)d_in[8];
    const float* Wl  = (const float*)d_in[9];
    const float* bl  = (const float*)d_in[10];

    const int N = in_sizes[0] / 128;
    const int E = in_sizes[1] / 2;
    const int* src = ei;
    const int* dst = ei + E;

    char* ws = (char*)d_ws;
    size_t off = 0;
    auto alloc = [&](size_t bytes) -> char* {
        char* p = ws + off;
        off += (bytes + 255) & ~(size_t)255;
        return p;
    };
    float* dis     = (float*)alloc((size_t)N * 4);
    int*   cnt     = (int*)  alloc((size_t)N * 4);      // histogram, later cursor
    int*   row_ptr = (int*)  alloc((size_t)(N + 1) * 4);
    int*   bsum    = (int*)  alloc(256 * 4);
    int*   csr     = (int*)  alloc((size_t)E * 4);
    float* A       = (float*)alloc((size_t)N * 84 * 4); // hh buffer
    float* B       = (float*)alloc((size_t)N * 84 * 4); // layer outputs 1,3
    float* C       = (float*)alloc((size_t)N * 64 * 4); // layer output 2
    float* D       = (float*)alloc((size_t)(64 * 32 + 64) * 4);

    dim3 blk(256);
    auto cdiv = [](long long a, long long b) { return (int)((a + b - 1) / b); };

    // ---- CSR build + normalization ----
    zero_int_k<<<cdiv(N, 256), blk, 0, stream>>>(cnt, N);
    hist_k<<<cdiv(E, 256), blk, 0, stream>>>(dst, cnt, E);
    dis_k<<<cdiv(N, 256), blk, 0, stream>>>(cnt, dis, N);
    int nb_scan = cdiv(N, 2048);
    scan_block_k<<<nb_scan, blk, 0, stream>>>(cnt, row_ptr, bsum, N);
    scan_partials_k<<<1, 64, 0, stream>>>(bsum, nb_scan);
    scan_add_k<<<cdiv(N, 256), blk, 0, stream>>>(row_ptr, bsum, cnt /*cursor*/, N, E);
    csr_fill_k<<<cdiv(E, 256), blk, 0, stream>>>(src, dst, cnt /*cursor*/, csr, E);

    // Layer 1: 128 -> 84
    gemm_scale_v2<128, 84, 48><<<cdiv(N, 48), blk, 0, stream>>>(x, W1, dis, A, N);
    aggregate_k<84><<<cdiv((long long)N * 84, 256), blk, 0, stream>>>(A, row_ptr, csr, dis, b1, B, N);

    // Layer 2: 84 -> 64
    gemm_scale_v2<84, 64, 64><<<cdiv(N, 64), blk, 0, stream>>>(B, W2, dis, A, N);
    aggregate_k<64><<<cdiv((long long)N * 64, 256), blk, 0, stream>>>(A, row_ptr, csr, dis, b2, C, N);

    // Layer 3: 64 -> 32
    gemm_scale_v2<64, 32, 128><<<cdiv(N, 128), blk, 0, stream>>>(C, W3, dis, A, N);
    aggregate_k<32><<<cdiv((long long)N * 32, 256), blk, 0, stream>>>(A, row_ptr, csr, dis, b3, B, N);

    // global mean pool + head
    zero_k<<<cdiv(64 * 32 + 64, 256), blk, 0, stream>>>(D, 64 * 32 + 64);
    pool2_k<<<cdiv(N, 1024), blk, 0, stream>>>(B, bat, D, D + 64 * 32, N);
    head_k<<<1, 128, 0, stream>>>(D, D + 64 * 32, Wl, bl, (float*)d_out);
}

// Round 6
// 630.936 us; speedup vs baseline: 3.5969x; 1.0077x over previous
//
#include <hip/hip_runtime.h>
#include <hip/hip_bf16.h>

// ---------------- utility ----------------

__global__ void zero_int_k(int* __restrict__ p, int n) {
    for (int i = blockIdx.x * blockDim.x + threadIdx.x; i < n;
         i += gridDim.x * blockDim.x)
        p[i] = 0;
}

__global__ void zero_k(float* __restrict__ p, int n) {
    for (int i = blockIdx.x * blockDim.x + threadIdx.x; i < n;
         i += gridDim.x * blockDim.x)
        p[i] = 0.0f;
}

// ---------------- CSR build ----------------

__global__ void hist_k(const int* __restrict__ dst, int* __restrict__ cnt, int E) {
    int i = blockIdx.x * blockDim.x + threadIdx.x;
    if (i < E) atomicAdd(&cnt[dst[i]], 1);
}

__global__ void dis_k(const int* __restrict__ cnt, float* __restrict__ dis, int n) {
    int i = blockIdx.x * blockDim.x + threadIdx.x;
    if (i < n) dis[i] = rsqrtf(1.0f + (float)cnt[i]);  // +1 self-loop
}

// exclusive scan, 2048 elements per block (256 thr x 8)
__global__ __launch_bounds__(256) void scan_block_k(
    const int* __restrict__ in, int* __restrict__ out,
    int* __restrict__ bsum, int n)
{
    __shared__ int ts[256];
    int base = blockIdx.x * 2048;
    int i0 = base + threadIdx.x * 8;
    int vals[8];
    int s = 0;
#pragma unroll
    for (int j = 0; j < 8; ++j) {
        int v = (i0 + j) < n ? in[i0 + j] : 0;
        vals[j] = v; s += v;
    }
    ts[threadIdx.x] = s;
    __syncthreads();
    for (int d = 1; d < 256; d <<= 1) {
        int t = (threadIdx.x >= (unsigned)d) ? ts[threadIdx.x - d] : 0;
        __syncthreads();
        ts[threadIdx.x] += t;
        __syncthreads();
    }
    int run = ts[threadIdx.x] - s;  // exclusive prefix of this thread
    if (threadIdx.x == 255) bsum[blockIdx.x] = ts[255];
#pragma unroll
    for (int j = 0; j < 8; ++j) {
        if (i0 + j < n) out[i0 + j] = run;
        run += vals[j];
    }
}

__global__ void scan_partials_k(int* __restrict__ bsum, int nb) {
    if (threadIdx.x == 0 && blockIdx.x == 0) {
        int run = 0;
        for (int i = 0; i < nb; ++i) { int t = bsum[i]; bsum[i] = run; run += t; }
    }
}

__global__ void scan_add_k(int* __restrict__ rp, const int* __restrict__ bsum,
                           int* __restrict__ cursor, int n, int E)
{
    int i = blockIdx.x * blockDim.x + threadIdx.x;
    if (i < n) {
        int v = rp[i] + bsum[i >> 11];
        rp[i] = v;
        cursor[i] = v;
    }
    if (i == 0) rp[n] = E;
}

__global__ void csr_fill_k(const int* __restrict__ src, const int* __restrict__ dst,
                           int* __restrict__ cursor, int* __restrict__ csr, int E)
{
    int i = blockIdx.x * blockDim.x + threadIdx.x;
    if (i < E) {
        int pos = atomicAdd(&cursor[dst[i]], 1);
        csr[pos] = src[i];
    }
}

// ---------------- GEMM v2: 4x4 register-blocked, transposed-x LDS ----------------
// hh[i][f] = bf16( (in[i]@W)[f] * dis[i] )  -- f32 accumulate, bf16 store.

template<int FIN, int FOUT, int TILE_R>
__global__ __launch_bounds__(256) void gemm_scale_v2(
    const float* __restrict__ in, const float* __restrict__ W,
    const float* __restrict__ dis, __hip_bfloat16* __restrict__ hh, int n)
{
    constexpr int RG = TILE_R / 4;
    constexpr int CG = FOUT / 4;
    constexpr int NMT = RG * CG;
    static_assert(NMT <= 256, "tile too big");
    static_assert((RG & 3) == 0, "swizzle needs RG multiple of 4");
    constexpr int SR = TILE_R + 4;
    __shared__ float Ws[FIN * FOUT];
    __shared__ float xs[FIN * SR];

    for (int i = threadIdx.x; i < FIN * FOUT; i += 256) Ws[i] = W[i];

    const int tid = threadIdx.x;
    const int rg = tid / CG;
    const int cg = tid - rg * CG;
    const bool active = tid < NMT;

    for (long long base = (long long)blockIdx.x * TILE_R; base < n;
         base += (long long)gridDim.x * TILE_R) {
        const int cnt = (int)((n - base) < TILE_R ? (n - base) : TILE_R);
        __syncthreads();
        for (int i = tid; i < TILE_R * (FIN / 4); i += 256) {
            int r  = i / (FIN / 4);
            int c4 = i - r * (FIN / 4);
            float4 v;
            if (r < cnt)
                v = *reinterpret_cast<const float4*>(&in[(base + r) * FIN + c4 * 4]);
            else
                v = make_float4(0.f, 0.f, 0.f, 0.f);
            int gph = (((r >> 2) ^ (c4 & 3)) << 2) + (r & 3);
            float* p = &xs[(c4 * 4) * SR + gph];
            p[0]      = v.x;
            p[SR]     = v.y;
            p[2 * SR] = v.z;
            p[3 * SR] = v.w;
        }
        __syncthreads();
        if (active) {
            float acc[4][4];
#pragma unroll
            for (int i = 0; i < 4; ++i)
#pragma unroll
                for (int j = 0; j < 4; ++j) acc[i][j] = 0.f;

#pragma unroll 8
            for (int k = 0; k < FIN; ++k) {
                float4 xa = *reinterpret_cast<const float4*>(
                    &xs[k * SR + ((rg ^ ((k >> 2) & 3)) << 2)]);
                float4 wb = *reinterpret_cast<const float4*>(&Ws[k * FOUT + cg * 4]);
                acc[0][0] = fmaf(xa.x, wb.x, acc[0][0]);
                acc[0][1] = fmaf(xa.x, wb.y, acc[0][1]);
                acc[0][2] = fmaf(xa.x, wb.z, acc[0][2]);
                acc[0][3] = fmaf(xa.x, wb.w, acc[0][3]);
                acc[1][0] = fmaf(xa.y, wb.x, acc[1][0]);
                acc[1][1] = fmaf(xa.y, wb.y, acc[1][1]);
                acc[1][2] = fmaf(xa.y, wb.z, acc[1][2]);
                acc[1][3] = fmaf(xa.y, wb.w, acc[1][3]);
                acc[2][0] = fmaf(xa.z, wb.x, acc[2][0]);
                acc[2][1] = fmaf(xa.z, wb.y, acc[2][1]);
                acc[2][2] = fmaf(xa.z, wb.z, acc[2][2]);
                acc[2][3] = fmaf(xa.z, wb.w, acc[2][3]);
                acc[3][0] = fmaf(xa.w, wb.x, acc[3][0]);
                acc[3][1] = fmaf(xa.w, wb.y, acc[3][1]);
                acc[3][2] = fmaf(xa.w, wb.z, acc[3][2]);
                acc[3][3] = fmaf(xa.w, wb.w, acc[3][3]);
            }
#pragma unroll
            for (int i = 0; i < 4; ++i) {
                int r = rg * 4 + i;
                if (r < cnt) {
                    float d = dis[base + r];
                    alignas(8) __hip_bfloat16 o[4];
                    o[0] = __float2bfloat16(acc[i][0] * d);
                    o[1] = __float2bfloat16(acc[i][1] * d);
                    o[2] = __float2bfloat16(acc[i][2] * d);
                    o[3] = __float2bfloat16(acc[i][3] * d);
                    // (node*FOUT + cg*4) is a multiple of 4 -> 8B aligned
                    *reinterpret_cast<uint2*>(
                        &hh[(size_t)(base + r) * FOUT + cg * 4]) =
                        *reinterpret_cast<const uint2*>(o);
                }
            }
        }
    }
}

// ---------------- CSR aggregate + bias + relu (bf16 messages, f32 sum) ----------------

template<int F>
__global__ __launch_bounds__(256) void aggregate_k(
    const __hip_bfloat16* __restrict__ hh, const int* __restrict__ row_ptr,
    const int* __restrict__ csr, const float* __restrict__ dis,
    const float* __restrict__ b, float* __restrict__ out, int n)
{
    long long idx = (long long)blockIdx.x * 256 + threadIdx.x;
    if (idx >= (long long)n * F) return;
    int node = (int)(idx / F);
    int f = (int)(idx - (long long)node * F);
    float a = __bfloat162float(hh[idx]);  // self-loop term
    int e = row_ptr[node];
    int e1 = row_ptr[node + 1];
    for (; e + 1 < e1; e += 2) {
        int s0 = csr[e], s1 = csr[e + 1];
        float v0 = __bfloat162float(hh[(size_t)s0 * F + f]);
        float v1 = __bfloat162float(hh[(size_t)s1 * F + f]);
        a += v0; a += v1;
    }
    if (e < e1) a += __bfloat162float(hh[(size_t)csr[e] * F + f]);
    out[idx] = fmaxf(fmaf(dis[node], a, b[f]), 0.0f);
}

// ---------------- pooling ----------------

__global__ __launch_bounds__(256) void pool2_k(
    const float* __restrict__ h, const int* __restrict__ batch,
    float* __restrict__ sums, float* __restrict__ cnt, int n)
{
    constexpr int CHUNK = 1024;
    __shared__ float s[64 * 32];
    __shared__ float sc[64];
    for (int i = threadIdx.x; i < 64 * 32; i += 256) s[i] = 0.0f;
    if (threadIdx.x < 64) sc[threadIdx.x] = 0.0f;
    __syncthreads();

    long long start = (long long)blockIdx.x * CHUNK;
    long long end = start + CHUNK < n ? start + CHUNK : n;
    int total = (int)(end - start) * 32;
    for (int i = threadIdx.x; i < total; i += 256) {
        int r = i >> 5;
        int f = i & 31;
        int node = (int)start + r;
        int g = batch[node];
        atomicAdd(&s[g * 32 + f], h[(size_t)node * 32 + f]);
        if (f == 0) atomicAdd(&sc[g], 1.0f);
    }
    __syncthreads();
    for (int i = threadIdx.x; i < 64 * 32; i += 256) {
        float v = s[i];
        if (v != 0.0f) atomicAdd(&sums[i], v);
    }
    if (threadIdx.x < 64) {
        float v = sc[threadIdx.x];
        if (v != 0.0f) atomicAdd(&cnt[threadIdx.x], v);
    }
}

__global__ void head_k(const float* __restrict__ sums, const float* __restrict__ cnt,
                       const float* __restrict__ Wl, const float* __restrict__ bl,
                       float* __restrict__ out)
{
    int tid = threadIdx.x;
    if (tid < 128) {
        int g = tid >> 1;
        int o = tid & 1;
        float c = fmaxf(cnt[g], 1.0f);
        float a = 0.0f;
#pragma unroll
        for (int f = 0; f < 32; ++f)
            a += (sums[g * 32 + f] / c) * Wl[f * 2 + o];
        out[tid] = a + bl[o];
    }
}

// ---------------- launch ----------------

extern "C" void kernel_launch(void* const* d_in, const int* in_sizes, int n_in,
                              void* d_out, int out_size, void* d_ws, size_t ws_size,
                              hipStream_t stream)
{
    const float* x   = (const float*)d_in[0];
    const int*   ei  = (const int*)d_in[1];
    const int*   bat = (const int*)d_in[2];
    const float* W1  = (const float*)d_in[3];
    const float* b1  = (const float*)d_in[4];
    const float* W2  = (const float*)d_in[5];
    const float* b2  = (const float*)d_in[6];
    const float* W3  = (const float*)d_in[7];
    const float* b3  = (const float*)d_in[8];
    const float* Wl  = (const float*)d_in[9];
    const float* bl  = (const float*)d_in[10];

    const int N = in_sizes[0] / 128;
    const int E = in_sizes[1] / 2;
    const int* src = ei;
    const int* dst = ei + E;

    char* ws = (char*)d_ws;
    size_t off = 0;
    auto alloc = [&](size_t bytes) -> char* {
        char* p = ws + off;
        off += (bytes + 255) & ~(size_t)255;
        return p;
    };
    float* dis     = (float*)alloc((size_t)N * 4);
    int*   cnt     = (int*)  alloc((size_t)N * 4);      // histogram, later cursor
    int*   row_ptr = (int*)  alloc((size_t)(N + 1) * 4);
    int*   bsum    = (int*)  alloc(256 * 4);
    int*   csr     = (int*)  alloc((size_t)E * 4);
    __hip_bfloat16* A = (__hip_bfloat16*)alloc((size_t)N * 84 * 2); // bf16 hh
    float* B       = (float*)alloc((size_t)N * 84 * 4); // layer outputs 1,3
    float* C       = (float*)alloc((size_t)N * 64 * 4); // layer output 2
    float* D       = (float*)alloc((size_t)(64 * 32 + 64) * 4);

    dim3 blk(256);
    auto cdiv = [](long long a, long long b) { return (int)((a + b - 1) / b); };

    // ---- CSR build + normalization ----
    zero_int_k<<<cdiv(N, 256), blk, 0, stream>>>(cnt, N);
    hist_k<<<cdiv(E, 256), blk, 0, stream>>>(dst, cnt, E);
    dis_k<<<cdiv(N, 256), blk, 0, stream>>>(cnt, dis, N);
    int nb_scan = cdiv(N, 2048);
    scan_block_k<<<nb_scan, blk, 0, stream>>>(cnt, row_ptr, bsum, N);
    scan_partials_k<<<1, 64, 0, stream>>>(bsum, nb_scan);
    scan_add_k<<<cdiv(N, 256), blk, 0, stream>>>(row_ptr, bsum, cnt /*cursor*/, N, E);
    csr_fill_k<<<cdiv(E, 256), blk, 0, stream>>>(src, dst, cnt /*cursor*/, csr, E);

    // Layer 1: 128 -> 84
    gemm_scale_v2<128, 84, 48><<<cdiv(N, 48), blk, 0, stream>>>(x, W1, dis, A, N);
    aggregate_k<84><<<cdiv((long long)N * 84, 256), blk, 0, stream>>>(A, row_ptr, csr, dis, b1, B, N);

    // Layer 2: 84 -> 64
    gemm_scale_v2<84, 64, 64><<<cdiv(N, 64), blk, 0, stream>>>(B, W2, dis, A, N);
    aggregate_k<64><<<cdiv((long long)N * 64, 256), blk, 0, stream>>>(A, row_ptr, csr, dis, b2, C, N);

    // Layer 3: 64 -> 32
    gemm_scale_v2<64, 32, 128><<<cdiv(N, 128), blk, 0, stream>>>(C, W3, dis, A, N);
    aggregate_k<32><<<cdiv((long long)N * 32, 256), blk, 0, stream>>>(A, row_ptr, csr, dis, b3, B, N);

    // global mean pool + head
    zero_k<<<cdiv(64 * 32 + 64, 256), blk, 0, stream>>>(D, 64 * 32 + 64);
    pool2_k<<<cdiv(N, 1024), blk, 0, stream>>>(B, bat, D, D + 64 * 32, N);
    head_k<<<1, 128, 0, stream>>>(D, D + 64 * 32, Wl, bl, (float*)d_out);
}

// Round 7
// 513.456 us; speedup vs baseline: 4.4199x; 1.2288x over previous
//
#include <hip/hip_runtime.h>
#include <hip/hip_bf16.h>

// ---------------- utility ----------------

__global__ void zero_int_k(int* __restrict__ p, int n) {
    for (int i = blockIdx.x * blockDim.x + threadIdx.x; i < n;
         i += gridDim.x * blockDim.x)
        p[i] = 0;
}

__global__ void zero_k(float* __restrict__ p, int n) {
    for (int i = blockIdx.x * blockDim.x + threadIdx.x; i < n;
         i += gridDim.x * blockDim.x)
        p[i] = 0.0f;
}

// ---------------- CSR build ----------------

__global__ void hist_k(const int* __restrict__ dst, int* __restrict__ cnt, int E) {
    int i = blockIdx.x * blockDim.x + threadIdx.x;
    if (i < E) atomicAdd(&cnt[dst[i]], 1);
}

__global__ void dis_k(const int* __restrict__ cnt, float* __restrict__ dis, int n) {
    int i = blockIdx.x * blockDim.x + threadIdx.x;
    if (i < n) dis[i] = rsqrtf(1.0f + (float)cnt[i]);  // +1 self-loop
}

// exclusive scan, 2048 elements per block (256 thr x 8)
__global__ __launch_bounds__(256) void scan_block_k(
    const int* __restrict__ in, int* __restrict__ out,
    int* __restrict__ bsum, int n)
{
    __shared__ int ts[256];
    int base = blockIdx.x * 2048;
    int i0 = base + threadIdx.x * 8;
    int vals[8];
    int s = 0;
#pragma unroll
    for (int j = 0; j < 8; ++j) {
        int v = (i0 + j) < n ? in[i0 + j] : 0;
        vals[j] = v; s += v;
    }
    ts[threadIdx.x] = s;
    __syncthreads();
    for (int d = 1; d < 256; d <<= 1) {
        int t = (threadIdx.x >= (unsigned)d) ? ts[threadIdx.x - d] : 0;
        __syncthreads();
        ts[threadIdx.x] += t;
        __syncthreads();
    }
    int run = ts[threadIdx.x] - s;  // exclusive prefix of this thread
    if (threadIdx.x == 255) bsum[blockIdx.x] = ts[255];
#pragma unroll
    for (int j = 0; j < 8; ++j) {
        if (i0 + j < n) out[i0 + j] = run;
        run += vals[j];
    }
}

__global__ void scan_partials_k(int* __restrict__ bsum, int nb) {
    if (threadIdx.x == 0 && blockIdx.x == 0) {
        int run = 0;
        for (int i = 0; i < nb; ++i) { int t = bsum[i]; bsum[i] = run; run += t; }
    }
}

__global__ void scan_add_k(int* __restrict__ rp, const int* __restrict__ bsum,
                           int* __restrict__ cursor, int n, int E)
{
    int i = blockIdx.x * blockDim.x + threadIdx.x;
    if (i < n) {
        int v = rp[i] + bsum[i >> 11];
        rp[i] = v;
        cursor[i] = v;
    }
    if (i == 0) rp[n] = E;
}

__global__ void csr_fill_k(const int* __restrict__ src, const int* __restrict__ dst,
                           int* __restrict__ cursor, int* __restrict__ csr, int E)
{
    int i = blockIdx.x * blockDim.x + threadIdx.x;
    if (i < E) {
        int pos = atomicAdd(&cursor[dst[i]], 1);
        csr[pos] = src[i];
    }
}

// ---------------- GEMM v2: 4x4 register-blocked, transposed-x LDS ----------------
// hh[i][f] = bf16( (in[i]@W)[f] * dis[i] )  -- f32 accumulate, bf16 store.

template<int FIN, int FOUT, int TILE_R>
__global__ __launch_bounds__(256) void gemm_scale_v2(
    const float* __restrict__ in, const float* __restrict__ W,
    const float* __restrict__ dis, __hip_bfloat16* __restrict__ hh, int n)
{
    constexpr int RG = TILE_R / 4;
    constexpr int CG = FOUT / 4;
    constexpr int NMT = RG * CG;
    static_assert(NMT <= 256, "tile too big");
    static_assert((RG & 3) == 0, "swizzle needs RG multiple of 4");
    constexpr int SR = TILE_R + 4;
    __shared__ float Ws[FIN * FOUT];
    __shared__ float xs[FIN * SR];

    for (int i = threadIdx.x; i < FIN * FOUT; i += 256) Ws[i] = W[i];

    const int tid = threadIdx.x;
    const int rg = tid / CG;
    const int cg = tid - rg * CG;
    const bool active = tid < NMT;

    for (long long base = (long long)blockIdx.x * TILE_R; base < n;
         base += (long long)gridDim.x * TILE_R) {
        const int cnt = (int)((n - base) < TILE_R ? (n - base) : TILE_R);
        __syncthreads();
        for (int i = tid; i < TILE_R * (FIN / 4); i += 256) {
            int r  = i / (FIN / 4);
            int c4 = i - r * (FIN / 4);
            float4 v;
            if (r < cnt)
                v = *reinterpret_cast<const float4*>(&in[(base + r) * FIN + c4 * 4]);
            else
                v = make_float4(0.f, 0.f, 0.f, 0.f);
            int gph = (((r >> 2) ^ (c4 & 3)) << 2) + (r & 3);
            float* p = &xs[(c4 * 4) * SR + gph];
            p[0]      = v.x;
            p[SR]     = v.y;
            p[2 * SR] = v.z;
            p[3 * SR] = v.w;
        }
        __syncthreads();
        if (active) {
            float acc[4][4];
#pragma unroll
            for (int i = 0; i < 4; ++i)
#pragma unroll
                for (int j = 0; j < 4; ++j) acc[i][j] = 0.f;

#pragma unroll 8
            for (int k = 0; k < FIN; ++k) {
                float4 xa = *reinterpret_cast<const float4*>(
                    &xs[k * SR + ((rg ^ ((k >> 2) & 3)) << 2)]);
                float4 wb = *reinterpret_cast<const float4*>(&Ws[k * FOUT + cg * 4]);
                acc[0][0] = fmaf(xa.x, wb.x, acc[0][0]);
                acc[0][1] = fmaf(xa.x, wb.y, acc[0][1]);
                acc[0][2] = fmaf(xa.x, wb.z, acc[0][2]);
                acc[0][3] = fmaf(xa.x, wb.w, acc[0][3]);
                acc[1][0] = fmaf(xa.y, wb.x, acc[1][0]);
                acc[1][1] = fmaf(xa.y, wb.y, acc[1][1]);
                acc[1][2] = fmaf(xa.y, wb.z, acc[1][2]);
                acc[1][3] = fmaf(xa.y, wb.w, acc[1][3]);
                acc[2][0] = fmaf(xa.z, wb.x, acc[2][0]);
                acc[2][1] = fmaf(xa.z, wb.y, acc[2][1]);
                acc[2][2] = fmaf(xa.z, wb.z, acc[2][2]);
                acc[2][3] = fmaf(xa.z, wb.w, acc[2][3]);
                acc[3][0] = fmaf(xa.w, wb.x, acc[3][0]);
                acc[3][1] = fmaf(xa.w, wb.y, acc[3][1]);
                acc[3][2] = fmaf(xa.w, wb.z, acc[3][2]);
                acc[3][3] = fmaf(xa.w, wb.w, acc[3][3]);
            }
#pragma unroll
            for (int i = 0; i < 4; ++i) {
                int r = rg * 4 + i;
                if (r < cnt) {
                    float d = dis[base + r];
                    alignas(8) __hip_bfloat16 o[4];
                    o[0] = __float2bfloat16(acc[i][0] * d);
                    o[1] = __float2bfloat16(acc[i][1] * d);
                    o[2] = __float2bfloat16(acc[i][2] * d);
                    o[3] = __float2bfloat16(acc[i][3] * d);
                    *reinterpret_cast<uint2*>(
                        &hh[(size_t)(base + r) * FOUT + cg * 4]) =
                        *reinterpret_cast<const uint2*>(o);
                }
            }
        }
    }
}

// ---------------- CSR aggregate: 8-deep MLP, bf16 messages, f32 sums ----------------
// out[d][f] = relu(dis[d]*(hh[d][f] + sum_e hh[csr[e]][f]) + b[f])
// 8 independent accumulators keep 8 gathers in flight per wave (latency-bound fix).

template<int F>
__global__ __launch_bounds__(256) void aggregate_k(
    const __hip_bfloat16* __restrict__ hh, const int* __restrict__ row_ptr,
    const int* __restrict__ csr, const float* __restrict__ dis,
    const float* __restrict__ b, float* __restrict__ out, int n)
{
    long long idx = (long long)blockIdx.x * 256 + threadIdx.x;
    if (idx >= (long long)n * F) return;
    int node = (int)(idx / F);
    int f = (int)(idx - (long long)node * F);
    int e = row_ptr[node];
    const int e1 = row_ptr[node + 1];

    float a0 = __bfloat162float(hh[idx]);  // self-loop
    float a1 = 0.f, a2 = 0.f, a3 = 0.f, a4 = 0.f, a5 = 0.f, a6 = 0.f, a7 = 0.f;

    for (; e + 8 <= e1; e += 8) {
        int s0 = csr[e],     s1 = csr[e + 1], s2 = csr[e + 2], s3 = csr[e + 3];
        int s4 = csr[e + 4], s5 = csr[e + 5], s6 = csr[e + 6], s7 = csr[e + 7];
        float v0 = __bfloat162float(hh[(size_t)s0 * F + f]);
        float v1 = __bfloat162float(hh[(size_t)s1 * F + f]);
        float v2 = __bfloat162float(hh[(size_t)s2 * F + f]);
        float v3 = __bfloat162float(hh[(size_t)s3 * F + f]);
        float v4 = __bfloat162float(hh[(size_t)s4 * F + f]);
        float v5 = __bfloat162float(hh[(size_t)s5 * F + f]);
        float v6 = __bfloat162float(hh[(size_t)s6 * F + f]);
        float v7 = __bfloat162float(hh[(size_t)s7 * F + f]);
        a0 += v0; a1 += v1; a2 += v2; a3 += v3;
        a4 += v4; a5 += v5; a6 += v6; a7 += v7;
    }
    if (e + 4 <= e1) {
        int s0 = csr[e], s1 = csr[e + 1], s2 = csr[e + 2], s3 = csr[e + 3];
        float v0 = __bfloat162float(hh[(size_t)s0 * F + f]);
        float v1 = __bfloat162float(hh[(size_t)s1 * F + f]);
        float v2 = __bfloat162float(hh[(size_t)s2 * F + f]);
        float v3 = __bfloat162float(hh[(size_t)s3 * F + f]);
        a0 += v0; a1 += v1; a2 += v2; a3 += v3;
        e += 4;
    }
    for (; e < e1; ++e)
        a0 += __bfloat162float(hh[(size_t)csr[e] * F + f]);

    float a = ((a0 + a1) + (a2 + a3)) + ((a4 + a5) + (a6 + a7));
    out[idx] = fmaxf(fmaf(dis[node], a, b[f]), 0.0f);
}

// ---------------- pooling ----------------

__global__ __launch_bounds__(256) void pool2_k(
    const float* __restrict__ h, const int* __restrict__ batch,
    float* __restrict__ sums, float* __restrict__ cnt, int n)
{
    constexpr int CHUNK = 1024;
    __shared__ float s[64 * 32];
    __shared__ float sc[64];
    for (int i = threadIdx.x; i < 64 * 32; i += 256) s[i] = 0.0f;
    if (threadIdx.x < 64) sc[threadIdx.x] = 0.0f;
    __syncthreads();

    long long start = (long long)blockIdx.x * CHUNK;
    long long end = start + CHUNK < n ? start + CHUNK : n;
    int total = (int)(end - start) * 32;
    for (int i = threadIdx.x; i < total; i += 256) {
        int r = i >> 5;
        int f = i & 31;
        int node = (int)start + r;
        int g = batch[node];
        atomicAdd(&s[g * 32 + f], h[(size_t)node * 32 + f]);
        if (f == 0) atomicAdd(&sc[g], 1.0f);
    }
    __syncthreads();
    for (int i = threadIdx.x; i < 64 * 32; i += 256) {
        float v = s[i];
        if (v != 0.0f) atomicAdd(&sums[i], v);
    }
    if (threadIdx.x < 64) {
        float v = sc[threadIdx.x];
        if (v != 0.0f) atomicAdd(&cnt[threadIdx.x], v);
    }
}

__global__ void head_k(const float* __restrict__ sums, const float* __restrict__ cnt,
                       const float* __restrict__ Wl, const float* __restrict__ bl,
                       float* __restrict__ out)
{
    int tid = threadIdx.x;
    if (tid < 128) {
        int g = tid >> 1;
        int o = tid & 1;
        float c = fmaxf(cnt[g], 1.0f);
        float a = 0.0f;
#pragma unroll
        for (int f = 0; f < 32; ++f)
            a += (sums[g * 32 + f] / c) * Wl[f * 2 + o];
        out[tid] = a + bl[o];
    }
}

// ---------------- launch ----------------

extern "C" void kernel_launch(void* const* d_in, const int* in_sizes, int n_in,
                              void* d_out, int out_size, void* d_ws, size_t ws_size,
                              hipStream_t stream)
{
    const float* x   = (const float*)d_in[0];
    const int*   ei  = (const int*)d_in[1];
    const int*   bat = (const int*)d_in[2];
    const float* W1  = (const float*)d_in[3];
    const float* b1  = (const float*)d_in[4];
    const float* W2  = (const float*)d_in[5];
    const float* b2  = (const float*)d_in[6];
    const float* W3  = (const float*)d_in[7];
    const float* b3  = (const float*)d_in[8];
    const float* Wl  = (const float*)d_in[9];
    const float* bl  = (const float*)d_in[10];

    const int N = in_sizes[0] / 128;
    const int E = in_sizes[1] / 2;
    const int* src = ei;
    const int* dst = ei + E;

    char* ws = (char*)d_ws;
    size_t off = 0;
    auto alloc = [&](size_t bytes) -> char* {
        char* p = ws + off;
        off += (bytes + 255) & ~(size_t)255;
        return p;
    };
    float* dis     = (float*)alloc((size_t)N * 4);
    int*   cnt     = (int*)  alloc((size_t)N * 4);      // histogram, later cursor
    int*   row_ptr = (int*)  alloc((size_t)(N + 1) * 4);
    int*   bsum    = (int*)  alloc(256 * 4);
    int*   csr     = (int*)  alloc((size_t)E * 4);
    __hip_bfloat16* A = (__hip_bfloat16*)alloc((size_t)N * 84 * 2); // bf16 hh
    float* B       = (float*)alloc((size_t)N * 84 * 4); // layer outputs 1,3
    float* C       = (float*)alloc((size_t)N * 64 * 4); // layer output 2
    float* D       = (float*)alloc((size_t)(64 * 32 + 64) * 4);

    dim3 blk(256);
    auto cdiv = [](long long a, long long b) { return (int)((a + b - 1) / b); };

    // ---- CSR build + normalization ----
    zero_int_k<<<cdiv(N, 256), blk, 0, stream>>>(cnt, N);
    hist_k<<<cdiv(E, 256), blk, 0, stream>>>(dst, cnt, E);
    dis_k<<<cdiv(N, 256), blk, 0, stream>>>(cnt, dis, N);
    int nb_scan = cdiv(N, 2048);
    scan_block_k<<<nb_scan, blk, 0, stream>>>(cnt, row_ptr, bsum, N);
    scan_partials_k<<<1, 64, 0, stream>>>(bsum, nb_scan);
    scan_add_k<<<cdiv(N, 256), blk, 0, stream>>>(row_ptr, bsum, cnt /*cursor*/, N, E);
    csr_fill_k<<<cdiv(E, 256), blk, 0, stream>>>(src, dst, cnt /*cursor*/, csr, E);

    // Layer 1: 128 -> 84
    gemm_scale_v2<128, 84, 48><<<cdiv(N, 48), blk, 0, stream>>>(x, W1, dis, A, N);
    aggregate_k<84><<<cdiv((long long)N * 84, 256), blk, 0, stream>>>(A, row_ptr, csr, dis, b1, B, N);

    // Layer 2: 84 -> 64
    gemm_scale_v2<84, 64, 64><<<cdiv(N, 64), blk, 0, stream>>>(B, W2, dis, A, N);
    aggregate_k<64><<<cdiv((long long)N * 64, 256), blk, 0, stream>>>(A, row_ptr, csr, dis, b2, C, N);

    // Layer 3: 64 -> 32
    gemm_scale_v2<64, 32, 128><<<cdiv(N, 128), blk, 0, stream>>>(C, W3, dis, A, N);
    aggregate_k<32><<<cdiv((long long)N * 32, 256), blk, 0, stream>>>(A, row_ptr, csr, dis, b3, B, N);

    // global mean pool + head
    zero_k<<<cdiv(64 * 32 + 64, 256), blk, 0, stream>>>(D, 64 * 32 + 64);
    pool2_k<<<cdiv(N, 1024), blk, 0, stream>>>(B, bat, D, D + 64 * 32, N);
    head_k<<<1, 128, 0, stream>>>(D, D + 64 * 32, Wl, bl, (float*)d_out);
}

// Round 8
// 439.040 us; speedup vs baseline: 5.1690x; 1.1695x over previous
//
#include <hip/hip_runtime.h>
#include <hip/hip_bf16.h>

// ---------------- utility ----------------

__global__ void zero_int_k(int* __restrict__ p, int n) {
    for (int i = blockIdx.x * blockDim.x + threadIdx.x; i < n;
         i += gridDim.x * blockDim.x)
        p[i] = 0;
}

__global__ void zero_k(float* __restrict__ p, int n) {
    for (int i = blockIdx.x * blockDim.x + threadIdx.x; i < n;
         i += gridDim.x * blockDim.x)
        p[i] = 0.0f;
}

// ---------------- CSR build ----------------

// histogram + per-edge rank (rank = # earlier edges with same dst)
__global__ void hist_rank_k(const int* __restrict__ dst, int* __restrict__ cnt,
                            int* __restrict__ rank, int E) {
    int i = blockIdx.x * blockDim.x + threadIdx.x;
    if (i < E) rank[i] = atomicAdd(&cnt[dst[i]], 1);
}

__global__ void dis_k(const int* __restrict__ cnt, float* __restrict__ dis, int n) {
    int i = blockIdx.x * blockDim.x + threadIdx.x;
    if (i < n) dis[i] = rsqrtf(1.0f + (float)cnt[i]);  // +1 self-loop
}

// exclusive scan, 2048 elements per block (256 thr x 8)
__global__ __launch_bounds__(256) void scan_block_k(
    const int* __restrict__ in, int* __restrict__ out,
    int* __restrict__ bsum, int n)
{
    __shared__ int ts[256];
    int base = blockIdx.x * 2048;
    int i0 = base + threadIdx.x * 8;
    int vals[8];
    int s = 0;
#pragma unroll
    for (int j = 0; j < 8; ++j) {
        int v = (i0 + j) < n ? in[i0 + j] : 0;
        vals[j] = v; s += v;
    }
    ts[threadIdx.x] = s;
    __syncthreads();
    for (int d = 1; d < 256; d <<= 1) {
        int t = (threadIdx.x >= (unsigned)d) ? ts[threadIdx.x - d] : 0;
        __syncthreads();
        ts[threadIdx.x] += t;
        __syncthreads();
    }
    int run = ts[threadIdx.x] - s;  // exclusive prefix of this thread
    if (threadIdx.x == 255) bsum[blockIdx.x] = ts[255];
#pragma unroll
    for (int j = 0; j < 8; ++j) {
        if (i0 + j < n) out[i0 + j] = run;
        run += vals[j];
    }
}

__global__ void scan_partials_k(int* __restrict__ bsum, int nb) {
    if (threadIdx.x == 0 && blockIdx.x == 0) {
        int run = 0;
        for (int i = 0; i < nb; ++i) { int t = bsum[i]; bsum[i] = run; run += t; }
    }
}

__global__ void scan_add_k(int* __restrict__ rp, const int* __restrict__ bsum,
                           int n, int E)
{
    int i = blockIdx.x * blockDim.x + threadIdx.x;
    if (i < n) rp[i] += bsum[i >> 11];
    if (i == 0) rp[n] = E;
}

// atomic-free fill, dst-range partitioned so scatter writes stay L2-resident
__global__ void csr_fill_pass_k(const int* __restrict__ src, const int* __restrict__ dst,
                                const int* __restrict__ rank,
                                const int* __restrict__ row_ptr,
                                int* __restrict__ csr, int E, int lo, int hi)
{
    int i = blockIdx.x * blockDim.x + threadIdx.x;
    if (i < E) {
        int d = dst[i];
        if (d >= lo && d < hi)
            csr[row_ptr[d] + rank[i]] = src[i];
    }
}

// ---------------- GEMM v2: 4x4 register-blocked, transposed-x LDS ----------------
// hh[i][f] = bf16( (in[i]@W)[f] * dis[i] )  -- f32 accumulate, bf16 store.

template<int FIN, int FOUT, int TILE_R>
__global__ __launch_bounds__(256) void gemm_scale_v2(
    const float* __restrict__ in, const float* __restrict__ W,
    const float* __restrict__ dis, __hip_bfloat16* __restrict__ hh, int n)
{
    constexpr int RG = TILE_R / 4;
    constexpr int CG = FOUT / 4;
    constexpr int NMT = RG * CG;
    static_assert(NMT <= 256, "tile too big");
    static_assert((RG & 3) == 0, "swizzle needs RG multiple of 4");
    constexpr int SR = TILE_R + 4;
    __shared__ float Ws[FIN * FOUT];
    __shared__ float xs[FIN * SR];

    for (int i = threadIdx.x; i < FIN * FOUT; i += 256) Ws[i] = W[i];

    const int tid = threadIdx.x;
    const int rg = tid / CG;
    const int cg = tid - rg * CG;
    const bool active = tid < NMT;

    for (long long base = (long long)blockIdx.x * TILE_R; base < n;
         base += (long long)gridDim.x * TILE_R) {
        const int cnt = (int)((n - base) < TILE_R ? (n - base) : TILE_R);
        __syncthreads();
        for (int i = tid; i < TILE_R * (FIN / 4); i += 256) {
            int r  = i / (FIN / 4);
            int c4 = i - r * (FIN / 4);
            float4 v;
            if (r < cnt)
                v = *reinterpret_cast<const float4*>(&in[(base + r) * FIN + c4 * 4]);
            else
                v = make_float4(0.f, 0.f, 0.f, 0.f);
            int gph = (((r >> 2) ^ (c4 & 3)) << 2) + (r & 3);
            float* p = &xs[(c4 * 4) * SR + gph];
            p[0]      = v.x;
            p[SR]     = v.y;
            p[2 * SR] = v.z;
            p[3 * SR] = v.w;
        }
        __syncthreads();
        if (active) {
            float acc[4][4];
#pragma unroll
            for (int i = 0; i < 4; ++i)
#pragma unroll
                for (int j = 0; j < 4; ++j) acc[i][j] = 0.f;

#pragma unroll 8
            for (int k = 0; k < FIN; ++k) {
                float4 xa = *reinterpret_cast<const float4*>(
                    &xs[k * SR + ((rg ^ ((k >> 2) & 3)) << 2)]);
                float4 wb = *reinterpret_cast<const float4*>(&Ws[k * FOUT + cg * 4]);
                acc[0][0] = fmaf(xa.x, wb.x, acc[0][0]);
                acc[0][1] = fmaf(xa.x, wb.y, acc[0][1]);
                acc[0][2] = fmaf(xa.x, wb.z, acc[0][2]);
                acc[0][3] = fmaf(xa.x, wb.w, acc[0][3]);
                acc[1][0] = fmaf(xa.y, wb.x, acc[1][0]);
                acc[1][1] = fmaf(xa.y, wb.y, acc[1][1]);
                acc[1][2] = fmaf(xa.y, wb.z, acc[1][2]);
                acc[1][3] = fmaf(xa.y, wb.w, acc[1][3]);
                acc[2][0] = fmaf(xa.z, wb.x, acc[2][0]);
                acc[2][1] = fmaf(xa.z, wb.y, acc[2][1]);
                acc[2][2] = fmaf(xa.z, wb.z, acc[2][2]);
                acc[2][3] = fmaf(xa.z, wb.w, acc[2][3]);
                acc[3][0] = fmaf(xa.w, wb.x, acc[3][0]);
                acc[3][1] = fmaf(xa.w, wb.y, acc[3][1]);
                acc[3][2] = fmaf(xa.w, wb.z, acc[3][2]);
                acc[3][3] = fmaf(xa.w, wb.w, acc[3][3]);
            }
#pragma unroll
            for (int i = 0; i < 4; ++i) {
                int r = rg * 4 + i;
                if (r < cnt) {
                    float d = dis[base + r];
                    alignas(8) __hip_bfloat16 o[4];
                    o[0] = __float2bfloat16(acc[i][0] * d);
                    o[1] = __float2bfloat16(acc[i][1] * d);
                    o[2] = __float2bfloat16(acc[i][2] * d);
                    o[3] = __float2bfloat16(acc[i][3] * d);
                    *reinterpret_cast<uint2*>(
                        &hh[(size_t)(base + r) * FOUT + cg * 4]) =
                        *reinterpret_cast<const uint2*>(o);
                }
            }
        }
    }
}

// ---------------- CSR aggregate: 8-deep MLP, bf16 messages, f32 sums ----------------

template<int F>
__global__ __launch_bounds__(256) void aggregate_k(
    const __hip_bfloat16* __restrict__ hh, const int* __restrict__ row_ptr,
    const int* __restrict__ csr, const float* __restrict__ dis,
    const float* __restrict__ b, float* __restrict__ out, int n)
{
    long long idx = (long long)blockIdx.x * 256 + threadIdx.x;
    if (idx >= (long long)n * F) return;
    int node = (int)(idx / F);
    int f = (int)(idx - (long long)node * F);
    int e = row_ptr[node];
    const int e1 = row_ptr[node + 1];

    float a0 = __bfloat162float(hh[idx]);  // self-loop
    float a1 = 0.f, a2 = 0.f, a3 = 0.f, a4 = 0.f, a5 = 0.f, a6 = 0.f, a7 = 0.f;

    for (; e + 8 <= e1; e += 8) {
        int s0 = csr[e],     s1 = csr[e + 1], s2 = csr[e + 2], s3 = csr[e + 3];
        int s4 = csr[e + 4], s5 = csr[e + 5], s6 = csr[e + 6], s7 = csr[e + 7];
        float v0 = __bfloat162float(hh[(size_t)s0 * F + f]);
        float v1 = __bfloat162float(hh[(size_t)s1 * F + f]);
        float v2 = __bfloat162float(hh[(size_t)s2 * F + f]);
        float v3 = __bfloat162float(hh[(size_t)s3 * F + f]);
        float v4 = __bfloat162float(hh[(size_t)s4 * F + f]);
        float v5 = __bfloat162float(hh[(size_t)s5 * F + f]);
        float v6 = __bfloat162float(hh[(size_t)s6 * F + f]);
        float v7 = __bfloat162float(hh[(size_t)s7 * F + f]);
        a0 += v0; a1 += v1; a2 += v2; a3 += v3;
        a4 += v4; a5 += v5; a6 += v6; a7 += v7;
    }
    if (e + 4 <= e1) {
        int s0 = csr[e], s1 = csr[e + 1], s2 = csr[e + 2], s3 = csr[e + 3];
        float v0 = __bfloat162float(hh[(size_t)s0 * F + f]);
        float v1 = __bfloat162float(hh[(size_t)s1 * F + f]);
        float v2 = __bfloat162float(hh[(size_t)s2 * F + f]);
        float v3 = __bfloat162float(hh[(size_t)s3 * F + f]);
        a0 += v0; a1 += v1; a2 += v2; a3 += v3;
        e += 4;
    }
    for (; e < e1; ++e)
        a0 += __bfloat162float(hh[(size_t)csr[e] * F + f]);

    float a = ((a0 + a1) + (a2 + a3)) + ((a4 + a5) + (a6 + a7));
    out[idx] = fmaxf(fmaf(dis[node], a, b[f]), 0.0f);
}

// ---------------- pooling ----------------

__global__ __launch_bounds__(256) void pool2_k(
    const float* __restrict__ h, const int* __restrict__ batch,
    float* __restrict__ sums, float* __restrict__ cnt, int n)
{
    constexpr int CHUNK = 1024;
    __shared__ float s[64 * 32];
    __shared__ float sc[64];
    for (int i = threadIdx.x; i < 64 * 32; i += 256) s[i] = 0.0f;
    if (threadIdx.x < 64) sc[threadIdx.x] = 0.0f;
    __syncthreads();

    long long start = (long long)blockIdx.x * CHUNK;
    long long end = start + CHUNK < n ? start + CHUNK : n;
    int total = (int)(end - start) * 32;
    for (int i = threadIdx.x; i < total; i += 256) {
        int r = i >> 5;
        int f = i & 31;
        int node = (int)start + r;
        int g = batch[node];
        atomicAdd(&s[g * 32 + f], h[(size_t)node * 32 + f]);
        if (f == 0) atomicAdd(&sc[g], 1.0f);
    }
    __syncthreads();
    for (int i = threadIdx.x; i < 64 * 32; i += 256) {
        float v = s[i];
        if (v != 0.0f) atomicAdd(&sums[i], v);
    }
    if (threadIdx.x < 64) {
        float v = sc[threadIdx.x];
        if (v != 0.0f) atomicAdd(&cnt[threadIdx.x], v);
    }
}

__global__ void head_k(const float* __restrict__ sums, const float* __restrict__ cnt,
                       const float* __restrict__ Wl, const float* __restrict__ bl,
                       float* __restrict__ out)
{
    int tid = threadIdx.x;
    if (tid < 128) {
        int g = tid >> 1;
        int o = tid & 1;
        float c = fmaxf(cnt[g], 1.0f);
        float a = 0.0f;
#pragma unroll
        for (int f = 0; f < 32; ++f)
            a += (sums[g * 32 + f] / c) * Wl[f * 2 + o];
        out[tid] = a + bl[o];
    }
}

// ---------------- launch ----------------

extern "C" void kernel_launch(void* const* d_in, const int* in_sizes, int n_in,
                              void* d_out, int out_size, void* d_ws, size_t ws_size,
                              hipStream_t stream)
{
    const float* x   = (const float*)d_in[0];
    const int*   ei  = (const int*)d_in[1];
    const int*   bat = (const int*)d_in[2];
    const float* W1  = (const float*)d_in[3];
    const float* b1  = (const float*)d_in[4];
    const float* W2  = (const float*)d_in[5];
    const float* b2  = (const float*)d_in[6];
    const float* W3  = (const float*)d_in[7];
    const float* b3  = (const float*)d_in[8];
    const float* Wl  = (const float*)d_in[9];
    const float* bl  = (const float*)d_in[10];

    const int N = in_sizes[0] / 128;
    const int E = in_sizes[1] / 2;
    const int* src = ei;
    const int* dst = ei + E;

    char* ws = (char*)d_ws;
    size_t off = 0;
    auto alloc = [&](size_t bytes) -> char* {
        char* p = ws + off;
        off += (bytes + 255) & ~(size_t)255;
        return p;
    };
    float* dis     = (float*)alloc((size_t)N * 4);
    int*   cnt     = (int*)  alloc((size_t)N * 4);      // histogram
    int*   row_ptr = (int*)  alloc((size_t)(N + 1) * 4);
    int*   bsum    = (int*)  alloc(256 * 4);
    int*   csr     = (int*)  alloc((size_t)E * 4);
    int*   rank    = (int*)  alloc((size_t)E * 4);
    __hip_bfloat16* A = (__hip_bfloat16*)alloc((size_t)N * 84 * 2); // bf16 hh
    float* B       = (float*)alloc((size_t)N * 84 * 4); // layer outputs 1,3
    float* C       = (float*)alloc((size_t)N * 64 * 4); // layer output 2
    float* D       = (float*)alloc((size_t)(64 * 32 + 64) * 4);

    dim3 blk(256);
    auto cdiv = [](long long a, long long b) { return (int)((a + b - 1) / b); };

    // ---- CSR build + normalization ----
    zero_int_k<<<cdiv(N, 256), blk, 0, stream>>>(cnt, N);
    hist_rank_k<<<cdiv(E, 256), blk, 0, stream>>>(dst, cnt, rank, E);
    dis_k<<<cdiv(N, 256), blk, 0, stream>>>(cnt, dis, N);
    int nb_scan = cdiv(N, 2048);
    scan_block_k<<<nb_scan, blk, 0, stream>>>(cnt, row_ptr, bsum, N);
    scan_partials_k<<<1, 64, 0, stream>>>(bsum, nb_scan);
    scan_add_k<<<cdiv(N, 256), blk, 0, stream>>>(row_ptr, bsum, N, E);
    constexpr int NPASS = 8;
    for (int p = 0; p < NPASS; ++p) {
        int lo = (int)((long long)N * p / NPASS);
        int hi = (int)((long long)N * (p + 1) / NPASS);
        csr_fill_pass_k<<<cdiv(E, 256), blk, 0, stream>>>(
            src, dst, rank, row_ptr, csr, E, lo, hi);
    }

    // Layer 1: 128 -> 84
    gemm_scale_v2<128, 84, 48><<<cdiv(N, 48), blk, 0, stream>>>(x, W1, dis, A, N);
    aggregate_k<84><<<cdiv((long long)N * 84, 256), blk, 0, stream>>>(A, row_ptr, csr, dis, b1, B, N);

    // Layer 2: 84 -> 64
    gemm_scale_v2<84, 64, 64><<<cdiv(N, 64), blk, 0, stream>>>(B, W2, dis, A, N);
    aggregate_k<64><<<cdiv((long long)N * 64, 256), blk, 0, stream>>>(A, row_ptr, csr, dis, b2, C, N);

    // Layer 3: 64 -> 32
    gemm_scale_v2<64, 32, 128><<<cdiv(N, 128), blk, 0, stream>>>(C, W3, dis, A, N);
    aggregate_k<32><<<cdiv((long long)N * 32, 256), blk, 0, stream>>>(A, row_ptr, csr, dis, b3, B, N);

    // global mean pool + head
    zero_k<<<cdiv(64 * 32 + 64, 256), blk, 0, stream>>>(D, 64 * 32 + 64);
    pool2_k<<<cdiv(N, 1024), blk, 0, stream>>>(B, bat, D, D + 64 * 32, N);
    head_k<<<1, 128, 0, stream>>>(D, D + 64 * 32, Wl, bl, (float*)d_out);
}

// Round 9
// 382.133 us; speedup vs baseline: 5.9388x; 1.1489x over previous
//
#include <hip/hip_runtime.h>
#include <hip/hip_bf16.h>

// ---------------- utility ----------------

__global__ void zero_int_k(int* __restrict__ p, int n) {
    for (int i = blockIdx.x * blockDim.x + threadIdx.x; i < n;
         i += gridDim.x * blockDim.x)
        p[i] = 0;
}

__global__ void zero_k(float* __restrict__ p, int n) {
    for (int i = blockIdx.x * blockDim.x + threadIdx.x; i < n;
         i += gridDim.x * blockDim.x)
        p[i] = 0.0f;
}

// ---------------- CSR build ----------------

__global__ void hist_rank_k(const int* __restrict__ dst, int* __restrict__ cnt,
                            int* __restrict__ rank, int E) {
    int i = blockIdx.x * blockDim.x + threadIdx.x;
    if (i < E) rank[i] = atomicAdd(&cnt[dst[i]], 1);
}

__global__ void dis_k(const int* __restrict__ cnt, float* __restrict__ dis, int n) {
    int i = blockIdx.x * blockDim.x + threadIdx.x;
    if (i < n) dis[i] = rsqrtf(1.0f + (float)cnt[i]);  // +1 self-loop
}

// exclusive scan, 2048 elements per block (256 thr x 8)
__global__ __launch_bounds__(256) void scan_block_k(
    const int* __restrict__ in, int* __restrict__ out,
    int* __restrict__ bsum, int n)
{
    __shared__ int ts[256];
    int base = blockIdx.x * 2048;
    int i0 = base + threadIdx.x * 8;
    int vals[8];
    int s = 0;
#pragma unroll
    for (int j = 0; j < 8; ++j) {
        int v = (i0 + j) < n ? in[i0 + j] : 0;
        vals[j] = v; s += v;
    }
    ts[threadIdx.x] = s;
    __syncthreads();
    for (int d = 1; d < 256; d <<= 1) {
        int t = (threadIdx.x >= (unsigned)d) ? ts[threadIdx.x - d] : 0;
        __syncthreads();
        ts[threadIdx.x] += t;
        __syncthreads();
    }
    int run = ts[threadIdx.x] - s;
    if (threadIdx.x == 255) bsum[blockIdx.x] = ts[255];
#pragma unroll
    for (int j = 0; j < 8; ++j) {
        if (i0 + j < n) out[i0 + j] = run;
        run += vals[j];
    }
}

__global__ void scan_partials_k(int* __restrict__ bsum, int nb) {
    if (threadIdx.x == 0 && blockIdx.x == 0) {
        int run = 0;
        for (int i = 0; i < nb; ++i) { int t = bsum[i]; bsum[i] = run; run += t; }
    }
}

__global__ void scan_add_k(int* __restrict__ rp, const int* __restrict__ bsum,
                           int n, int E)
{
    int i = blockIdx.x * blockDim.x + threadIdx.x;
    if (i < n) rp[i] += bsum[i >> 11];
    if (i == 0) rp[n] = E;
}

// atomic-free fill, dst-range partitioned so scatter writes stay L2-resident
__global__ void csr_fill_pass_k(const int* __restrict__ src, const int* __restrict__ dst,
                                const int* __restrict__ rank,
                                const int* __restrict__ row_ptr,
                                int* __restrict__ csr, int E, int lo, int hi)
{
    int i = blockIdx.x * blockDim.x + threadIdx.x;
    if (i < E) {
        int d = dst[i];
        if (d >= lo && d < hi)
            csr[row_ptr[d] + rank[i]] = src[i];
    }
}

// ---------------- GEMM v2: 4x4 register-blocked, transposed-x LDS ----------------
// hh[i][f] = bf16( (in[i]@W)[f] * dis[i] )  -- f32 accumulate, bf16 store.

template<int FIN, int FOUT, int TILE_R>
__global__ __launch_bounds__(256) void gemm_scale_v2(
    const float* __restrict__ in, const float* __restrict__ W,
    const float* __restrict__ dis, __hip_bfloat16* __restrict__ hh, int n)
{
    constexpr int RG = TILE_R / 4;
    constexpr int CG = FOUT / 4;
    constexpr int NMT = RG * CG;
    static_assert(NMT <= 256, "tile too big");
    static_assert((RG & 3) == 0, "swizzle needs RG multiple of 4");
    constexpr int SR = TILE_R + 4;
    __shared__ float Ws[FIN * FOUT];
    __shared__ float xs[FIN * SR];

    for (int i = threadIdx.x; i < FIN * FOUT; i += 256) Ws[i] = W[i];

    const int tid = threadIdx.x;
    const int rg = tid / CG;
    const int cg = tid - rg * CG;
    const bool active = tid < NMT;

    for (long long base = (long long)blockIdx.x * TILE_R; base < n;
         base += (long long)gridDim.x * TILE_R) {
        const int cnt = (int)((n - base) < TILE_R ? (n - base) : TILE_R);
        __syncthreads();
        for (int i = tid; i < TILE_R * (FIN / 4); i += 256) {
            int r  = i / (FIN / 4);
            int c4 = i - r * (FIN / 4);
            float4 v;
            if (r < cnt)
                v = *reinterpret_cast<const float4*>(&in[(base + r) * FIN + c4 * 4]);
            else
                v = make_float4(0.f, 0.f, 0.f, 0.f);
            int gph = (((r >> 2) ^ (c4 & 3)) << 2) + (r & 3);
            float* p = &xs[(c4 * 4) * SR + gph];
            p[0]      = v.x;
            p[SR]     = v.y;
            p[2 * SR] = v.z;
            p[3 * SR] = v.w;
        }
        __syncthreads();
        if (active) {
            float acc[4][4];
#pragma unroll
            for (int i = 0; i < 4; ++i)
#pragma unroll
                for (int j = 0; j < 4; ++j) acc[i][j] = 0.f;

#pragma unroll 8
            for (int k = 0; k < FIN; ++k) {
                float4 xa = *reinterpret_cast<const float4*>(
                    &xs[k * SR + ((rg ^ ((k >> 2) & 3)) << 2)]);
                float4 wb = *reinterpret_cast<const float4*>(&Ws[k * FOUT + cg * 4]);
                acc[0][0] = fmaf(xa.x, wb.x, acc[0][0]);
                acc[0][1] = fmaf(xa.x, wb.y, acc[0][1]);
                acc[0][2] = fmaf(xa.x, wb.z, acc[0][2]);
                acc[0][3] = fmaf(xa.x, wb.w, acc[0][3]);
                acc[1][0] = fmaf(xa.y, wb.x, acc[1][0]);
                acc[1][1] = fmaf(xa.y, wb.y, acc[1][1]);
                acc[1][2] = fmaf(xa.y, wb.z, acc[1][2]);
                acc[1][3] = fmaf(xa.y, wb.w, acc[1][3]);
                acc[2][0] = fmaf(xa.z, wb.x, acc[2][0]);
                acc[2][1] = fmaf(xa.z, wb.y, acc[2][1]);
                acc[2][2] = fmaf(xa.z, wb.z, acc[2][2]);
                acc[2][3] = fmaf(xa.z, wb.w, acc[2][3]);
                acc[3][0] = fmaf(xa.w, wb.x, acc[3][0]);
                acc[3][1] = fmaf(xa.w, wb.y, acc[3][1]);
                acc[3][2] = fmaf(xa.w, wb.z, acc[3][2]);
                acc[3][3] = fmaf(xa.w, wb.w, acc[3][3]);
            }
#pragma unroll
            for (int i = 0; i < 4; ++i) {
                int r = rg * 4 + i;
                if (r < cnt) {
                    float d = dis[base + r];
                    alignas(8) __hip_bfloat16 o[4];
                    o[0] = __float2bfloat16(acc[i][0] * d);
                    o[1] = __float2bfloat16(acc[i][1] * d);
                    o[2] = __float2bfloat16(acc[i][2] * d);
                    o[3] = __float2bfloat16(acc[i][3] * d);
                    *reinterpret_cast<uint2*>(
                        &hh[(size_t)(base + r) * FOUT + cg * 4]) =
                        *reinterpret_cast<const uint2*>(o);
                }
            }
        }
    }
}

// ---------------- CSR aggregate v2: uint2 gathers (4 bf16/lane), 4-deep MLP ----------------
// thread = (node, 4-feature group). 4x fewer vmem instructions than 1-feat/thread.

template<int F>
__global__ __launch_bounds__(256) void aggregate_v2(
    const __hip_bfloat16* __restrict__ hh, const int* __restrict__ row_ptr,
    const int* __restrict__ csr, const float* __restrict__ dis,
    const float* __restrict__ b, float* __restrict__ out, int n)
{
    constexpr int FG = F / 4;  // feature groups per node
    long long idx = (long long)blockIdx.x * 256 + threadIdx.x;
    if (idx >= (long long)n * FG) return;
    int node = (int)(idx / FG);
    int fg = (int)(idx - (long long)node * FG);
    const int bf = fg * 4;

    const unsigned short* hs = (const unsigned short*)hh;
    auto lo16 = [](unsigned u) { return __uint_as_float(u << 16); };
    auto hi16 = [](unsigned u) { return __uint_as_float(u & 0xFFFF0000u); };

    uint2 su = *reinterpret_cast<const uint2*>(&hs[(size_t)node * F + bf]);
    float a0 = lo16(su.x), a1 = hi16(su.x), a2 = lo16(su.y), a3 = hi16(su.y);
    float c0 = 0.f, c1 = 0.f, c2 = 0.f, c3 = 0.f;

    int e = row_ptr[node];
    const int e1 = row_ptr[node + 1];
    for (; e + 4 <= e1; e += 4) {
        int s0 = csr[e], s1 = csr[e + 1], s2 = csr[e + 2], s3 = csr[e + 3];
        uint2 u0 = *reinterpret_cast<const uint2*>(&hs[(size_t)s0 * F + bf]);
        uint2 u1 = *reinterpret_cast<const uint2*>(&hs[(size_t)s1 * F + bf]);
        uint2 u2 = *reinterpret_cast<const uint2*>(&hs[(size_t)s2 * F + bf]);
        uint2 u3 = *reinterpret_cast<const uint2*>(&hs[(size_t)s3 * F + bf]);
        a0 += lo16(u0.x); a1 += hi16(u0.x); a2 += lo16(u0.y); a3 += hi16(u0.y);
        c0 += lo16(u1.x); c1 += hi16(u1.x); c2 += lo16(u1.y); c3 += hi16(u1.y);
        a0 += lo16(u2.x); a1 += hi16(u2.x); a2 += lo16(u2.y); a3 += hi16(u2.y);
        c0 += lo16(u3.x); c1 += hi16(u3.x); c2 += lo16(u3.y); c3 += hi16(u3.y);
    }
    for (; e < e1; ++e) {
        int s = csr[e];
        uint2 u = *reinterpret_cast<const uint2*>(&hs[(size_t)s * F + bf]);
        a0 += lo16(u.x); a1 += hi16(u.x); a2 += lo16(u.y); a3 += hi16(u.y);
    }
    a0 += c0; a1 += c1; a2 += c2; a3 += c3;

    float d = dis[node];
    float4 bb = *reinterpret_cast<const float4*>(&b[bf]);
    float4 o;
    o.x = fmaxf(fmaf(d, a0, bb.x), 0.0f);
    o.y = fmaxf(fmaf(d, a1, bb.y), 0.0f);
    o.z = fmaxf(fmaf(d, a2, bb.z), 0.0f);
    o.w = fmaxf(fmaf(d, a3, bb.w), 0.0f);
    *reinterpret_cast<float4*>(&out[(size_t)node * F + bf]) = o;
}

// ---------------- pooling ----------------

__global__ __launch_bounds__(256) void pool2_k(
    const float* __restrict__ h, const int* __restrict__ batch,
    float* __restrict__ sums, float* __restrict__ cnt, int n)
{
    constexpr int CHUNK = 1024;
    __shared__ float s[64 * 32];
    __shared__ float sc[64];
    for (int i = threadIdx.x; i < 64 * 32; i += 256) s[i] = 0.0f;
    if (threadIdx.x < 64) sc[threadIdx.x] = 0.0f;
    __syncthreads();

    long long start = (long long)blockIdx.x * CHUNK;
    long long end = start + CHUNK < n ? start + CHUNK : n;
    int total = (int)(end - start) * 32;
    for (int i = threadIdx.x; i < total; i += 256) {
        int r = i >> 5;
        int f = i & 31;
        int node = (int)start + r;
        int g = batch[node];
        atomicAdd(&s[g * 32 + f], h[(size_t)node * 32 + f]);
        if (f == 0) atomicAdd(&sc[g], 1.0f);
    }
    __syncthreads();
    for (int i = threadIdx.x; i < 64 * 32; i += 256) {
        float v = s[i];
        if (v != 0.0f) atomicAdd(&sums[i], v);
    }
    if (threadIdx.x < 64) {
        float v = sc[threadIdx.x];
        if (v != 0.0f) atomicAdd(&cnt[threadIdx.x], v);
    }
}

__global__ void head_k(const float* __restrict__ sums, const float* __restrict__ cnt,
                       const float* __restrict__ Wl, const float* __restrict__ bl,
                       float* __restrict__ out)
{
    int tid = threadIdx.x;
    if (tid < 128) {
        int g = tid >> 1;
        int o = tid & 1;
        float c = fmaxf(cnt[g], 1.0f);
        float a = 0.0f;
#pragma unroll
        for (int f = 0; f < 32; ++f)
            a += (sums[g * 32 + f] / c) * Wl[f * 2 + o];
        out[tid] = a + bl[o];
    }
}

// ---------------- launch ----------------

extern "C" void kernel_launch(void* const* d_in, const int* in_sizes, int n_in,
                              void* d_out, int out_size, void* d_ws, size_t ws_size,
                              hipStream_t stream)
{
    const float* x   = (const float*)d_in[0];
    const int*   ei  = (const int*)d_in[1];
    const int*   bat = (const int*)d_in[2];
    const float* W1  = (const float*)d_in[3];
    const float* b1  = (const float*)d_in[4];
    const float* W2  = (const float*)d_in[5];
    const float* b2  = (const float*)d_in[6];
    const float* W3  = (const float*)d_in[7];
    const float* b3  = (const float*)d_in[8];
    const float* Wl  = (const float*)d_in[9];
    const float* bl  = (const float*)d_in[10];

    const int N = in_sizes[0] / 128;
    const int E = in_sizes[1] / 2;
    const int* src = ei;
    const int* dst = ei + E;

    char* ws = (char*)d_ws;
    size_t off = 0;
    auto alloc = [&](size_t bytes) -> char* {
        char* p = ws + off;
        off += (bytes + 255) & ~(size_t)255;
        return p;
    };
    float* dis     = (float*)alloc((size_t)N * 4);
    int*   cnt     = (int*)  alloc((size_t)N * 4);
    int*   row_ptr = (int*)  alloc((size_t)(N + 1) * 4);
    int*   bsum    = (int*)  alloc(256 * 4);
    int*   csr     = (int*)  alloc((size_t)E * 4);
    int*   rank    = (int*)  alloc((size_t)E * 4);
    __hip_bfloat16* A = (__hip_bfloat16*)alloc((size_t)N * 84 * 2); // bf16 hh
    float* B       = (float*)alloc((size_t)N * 84 * 4); // layer outputs 1,3
    float* C       = (float*)alloc((size_t)N * 64 * 4); // layer output 2
    float* D       = (float*)alloc((size_t)(64 * 32 + 64) * 4);

    dim3 blk(256);
    auto cdiv = [](long long a, long long b) { return (int)((a + b - 1) / b); };

    // ---- CSR build + normalization ----
    zero_int_k<<<cdiv(N, 256), blk, 0, stream>>>(cnt, N);
    hist_rank_k<<<cdiv(E, 256), blk, 0, stream>>>(dst, cnt, rank, E);
    dis_k<<<cdiv(N, 256), blk, 0, stream>>>(cnt, dis, N);
    int nb_scan = cdiv(N, 2048);
    scan_block_k<<<nb_scan, blk, 0, stream>>>(cnt, row_ptr, bsum, N);
    scan_partials_k<<<1, 64, 0, stream>>>(bsum, nb_scan);
    scan_add_k<<<cdiv(N, 256), blk, 0, stream>>>(row_ptr, bsum, N, E);
    constexpr int NPASS = 4;
    for (int p = 0; p < NPASS; ++p) {
        int lo = (int)((long long)N * p / NPASS);
        int hi = (int)((long long)N * (p + 1) / NPASS);
        csr_fill_pass_k<<<cdiv(E, 256), blk, 0, stream>>>(
            src, dst, rank, row_ptr, csr, E, lo, hi);
    }

    // Layer 1: 128 -> 84
    gemm_scale_v2<128, 84, 48><<<cdiv(N, 48), blk, 0, stream>>>(x, W1, dis, A, N);
    aggregate_v2<84><<<cdiv((long long)N * 21, 256), blk, 0, stream>>>(A, row_ptr, csr, dis, b1, B, N);

    // Layer 2: 84 -> 64
    gemm_scale_v2<84, 64, 64><<<cdiv(N, 64), blk, 0, stream>>>(B, W2, dis, A, N);
    aggregate_v2<64><<<cdiv((long long)N * 16, 256), blk, 0, stream>>>(A, row_ptr, csr, dis, b2, C, N);

    // Layer 3: 64 -> 32
    gemm_scale_v2<64, 32, 128><<<cdiv(N, 128), blk, 0, stream>>>(C, W3, dis, A, N);
    aggregate_v2<32><<<cdiv((long long)N * 8, 256), blk, 0, stream>>>(A, row_ptr, csr, dis, b3, B, N);

    // global mean pool + head
    zero_k<<<cdiv(64 * 32 + 64, 256), blk, 0, stream>>>(D, 64 * 32 + 64);
    pool2_k<<<cdiv(N, 1024), blk, 0, stream>>>(B, bat, D, D + 64 * 32, N);
    head_k<<<1, 128, 0, stream>>>(D, D + 64 * 32, Wl, bl, (float*)d_out);
}

// Round 10
// 336.495 us; speedup vs baseline: 6.7443x; 1.1356x over previous
//
#include <hip/hip_runtime.h>
#include <hip/hip_bf16.h>

// ---------------- utility ----------------

__global__ void zero_k(float* __restrict__ p, int n) {
    for (int i = blockIdx.x * blockDim.x + threadIdx.x; i < n;
         i += gridDim.x * blockDim.x)
        p[i] = 0.0f;
}

// ---------------- bucketed CSR build (no global atomics) ----------------
// bucket = dst >> 8 (256 nodes/bucket). NB <= 512 supported.

__global__ __launch_bounds__(256) void bucket_hist_k(
    const int* __restrict__ dst, int* __restrict__ T, int E, int NB)
{
    __shared__ int hist[512];
    for (int b = threadIdx.x; b < NB; b += 256) hist[b] = 0;
    __syncthreads();
    int per = (E + gridDim.x - 1) / gridDim.x;
    int s = blockIdx.x * per;
    int e = min(E, s + per);
    for (int i = s + threadIdx.x; i < e; i += 256)
        atomicAdd(&hist[dst[i] >> 8], 1);
    __syncthreads();
    for (int b = threadIdx.x; b < NB; b += 256)
        T[b * gridDim.x + blockIdx.x] = hist[b];
}

// exclusive scan, 2048 elements per block (256 thr x 8)
__global__ __launch_bounds__(256) void scan_block_k(
    const int* __restrict__ in, int* __restrict__ out,
    int* __restrict__ bsum, int n)
{
    __shared__ int ts[256];
    int base = blockIdx.x * 2048;
    int i0 = base + threadIdx.x * 8;
    int vals[8];
    int s = 0;
#pragma unroll
    for (int j = 0; j < 8; ++j) {
        int v = (i0 + j) < n ? in[i0 + j] : 0;
        vals[j] = v; s += v;
    }
    ts[threadIdx.x] = s;
    __syncthreads();
    for (int d = 1; d < 256; d <<= 1) {
        int t = (threadIdx.x >= (unsigned)d) ? ts[threadIdx.x - d] : 0;
        __syncthreads();
        ts[threadIdx.x] += t;
        __syncthreads();
    }
    int run = ts[threadIdx.x] - s;
    if (threadIdx.x == 255) bsum[blockIdx.x] = ts[255];
#pragma unroll
    for (int j = 0; j < 8; ++j) {
        if (i0 + j < n) out[i0 + j] = run;
        run += vals[j];
    }
}

__global__ void scan_partials_k(int* __restrict__ bsum, int nb) {
    if (threadIdx.x == 0 && blockIdx.x == 0) {
        int run = 0;
        for (int i = 0; i < nb; ++i) { int t = bsum[i]; bsum[i] = run; run += t; }
    }
}

// adds block offsets; also writes rp[n] = E (used as scan total sentinel)
__global__ void scan_add_k(int* __restrict__ rp, const int* __restrict__ bsum,
                           int n, int E)
{
    int i = blockIdx.x * blockDim.x + threadIdx.x;
    if (i < n) rp[i] += bsum[i >> 11];
    if (i == 0) rp[n] = E;
}

__global__ __launch_bounds__(256) void bucket_scatter_k(
    const int* __restrict__ src, const int* __restrict__ dst,
    const int* __restrict__ Tsc, uint2* __restrict__ pairs, int E, int NB)
{
    __shared__ int cur[512];
    for (int b = threadIdx.x; b < NB; b += 256)
        cur[b] = Tsc[b * gridDim.x + blockIdx.x];
    __syncthreads();
    int per = (E + gridDim.x - 1) / gridDim.x;
    int s = blockIdx.x * per;
    int e = min(E, s + per);
    for (int i = s + threadIdx.x; i < e; i += 256) {
        int d = dst[i];
        int pos = atomicAdd(&cur[d >> 8], 1);
        pairs[pos] = make_uint2((unsigned)d, (unsigned)src[i]);
    }
}

// per-bucket: count -> LDS scan -> row_ptr + dis + csr fill (all LDS atomics)
__global__ __launch_bounds__(256) void bucket_csr_k(
    const uint2* __restrict__ pairs, const int* __restrict__ Tsc,
    int* __restrict__ row_ptr, float* __restrict__ dis,
    int* __restrict__ csr, int N, int E, int NB, int G)
{
    __shared__ int cnt[256];
    __shared__ int ts[256];
    __shared__ int cur[256];
    const int b = blockIdx.x;
    const int node0 = b << 8;
    const int e0 = Tsc[b * G];
    const int e1 = Tsc[(b + 1) * G];  // b==NB-1 reads Tsc[NB*G] == E
    const int j = threadIdx.x;
    cnt[j] = 0;
    __syncthreads();
    for (int i = e0 + j; i < e1; i += 256)
        atomicAdd(&cnt[pairs[i].x & 255u], 1);
    __syncthreads();
    int c = cnt[j];
    ts[j] = c;
    __syncthreads();
    for (int d = 1; d < 256; d <<= 1) {
        int t = (j >= d) ? ts[j - d] : 0;
        __syncthreads();
        ts[j] += t;
        __syncthreads();
    }
    int excl = ts[j] - c;
    int node = node0 + j;
    if (node < N) {
        row_ptr[node] = e0 + excl;
        dis[node] = rsqrtf(1.0f + (float)c);
    }
    cur[j] = e0 + excl;
    if (b == NB - 1 && j == 0) row_ptr[N] = E;
    __syncthreads();
    for (int i = e0 + j; i < e1; i += 256) {
        uint2 p = pairs[i];
        int pos = atomicAdd(&cur[p.x & 255u], 1);
        csr[pos] = (int)p.y;
    }
}

// ---------------- GEMM v2: 4x4 register-blocked, transposed-x LDS ----------------
// hh[i][f] = bf16( (in[i]@W)[f] * dis[i] )  -- f32 accumulate, bf16 store.

template<int FIN, int FOUT, int TILE_R>
__global__ __launch_bounds__(256) void gemm_scale_v2(
    const float* __restrict__ in, const float* __restrict__ W,
    const float* __restrict__ dis, __hip_bfloat16* __restrict__ hh, int n)
{
    constexpr int RG = TILE_R / 4;
    constexpr int CG = FOUT / 4;
    constexpr int NMT = RG * CG;
    static_assert(NMT <= 256, "tile too big");
    static_assert((RG & 3) == 0, "swizzle needs RG multiple of 4");
    constexpr int SR = TILE_R + 4;
    __shared__ float Ws[FIN * FOUT];
    __shared__ float xs[FIN * SR];

    for (int i = threadIdx.x; i < FIN * FOUT; i += 256) Ws[i] = W[i];

    const int tid = threadIdx.x;
    const int rg = tid / CG;
    const int cg = tid - rg * CG;
    const bool active = tid < NMT;

    for (long long base = (long long)blockIdx.x * TILE_R; base < n;
         base += (long long)gridDim.x * TILE_R) {
        const int cnt = (int)((n - base) < TILE_R ? (n - base) : TILE_R);
        __syncthreads();
        for (int i = tid; i < TILE_R * (FIN / 4); i += 256) {
            int r  = i / (FIN / 4);
            int c4 = i - r * (FIN / 4);
            float4 v;
            if (r < cnt)
                v = *reinterpret_cast<const float4*>(&in[(base + r) * FIN + c4 * 4]);
            else
                v = make_float4(0.f, 0.f, 0.f, 0.f);
            int gph = (((r >> 2) ^ (c4 & 3)) << 2) + (r & 3);
            float* p = &xs[(c4 * 4) * SR + gph];
            p[0]      = v.x;
            p[SR]     = v.y;
            p[2 * SR] = v.z;
            p[3 * SR] = v.w;
        }
        __syncthreads();
        if (active) {
            float acc[4][4];
#pragma unroll
            for (int i = 0; i < 4; ++i)
#pragma unroll
                for (int j = 0; j < 4; ++j) acc[i][j] = 0.f;

#pragma unroll 8
            for (int k = 0; k < FIN; ++k) {
                float4 xa = *reinterpret_cast<const float4*>(
                    &xs[k * SR + ((rg ^ ((k >> 2) & 3)) << 2)]);
                float4 wb = *reinterpret_cast<const float4*>(&Ws[k * FOUT + cg * 4]);
                acc[0][0] = fmaf(xa.x, wb.x, acc[0][0]);
                acc[0][1] = fmaf(xa.x, wb.y, acc[0][1]);
                acc[0][2] = fmaf(xa.x, wb.z, acc[0][2]);
                acc[0][3] = fmaf(xa.x, wb.w, acc[0][3]);
                acc[1][0] = fmaf(xa.y, wb.x, acc[1][0]);
                acc[1][1] = fmaf(xa.y, wb.y, acc[1][1]);
                acc[1][2] = fmaf(xa.y, wb.z, acc[1][2]);
                acc[1][3] = fmaf(xa.y, wb.w, acc[1][3]);
                acc[2][0] = fmaf(xa.z, wb.x, acc[2][0]);
                acc[2][1] = fmaf(xa.z, wb.y, acc[2][1]);
                acc[2][2] = fmaf(xa.z, wb.z, acc[2][2]);
                acc[2][3] = fmaf(xa.z, wb.w, acc[2][3]);
                acc[3][0] = fmaf(xa.w, wb.x, acc[3][0]);
                acc[3][1] = fmaf(xa.w, wb.y, acc[3][1]);
                acc[3][2] = fmaf(xa.w, wb.z, acc[3][2]);
                acc[3][3] = fmaf(xa.w, wb.w, acc[3][3]);
            }
#pragma unroll
            for (int i = 0; i < 4; ++i) {
                int r = rg * 4 + i;
                if (r < cnt) {
                    float d = dis[base + r];
                    alignas(8) __hip_bfloat16 o[4];
                    o[0] = __float2bfloat16(acc[i][0] * d);
                    o[1] = __float2bfloat16(acc[i][1] * d);
                    o[2] = __float2bfloat16(acc[i][2] * d);
                    o[3] = __float2bfloat16(acc[i][3] * d);
                    *reinterpret_cast<uint2*>(
                        &hh[(size_t)(base + r) * FOUT + cg * 4]) =
                        *reinterpret_cast<const uint2*>(o);
                }
            }
        }
    }
}

// ---------------- CSR aggregate v2: uint2 gathers (4 bf16/lane), 4-deep MLP ----------------

template<int F>
__global__ __launch_bounds__(256) void aggregate_v2(
    const __hip_bfloat16* __restrict__ hh, const int* __restrict__ row_ptr,
    const int* __restrict__ csr, const float* __restrict__ dis,
    const float* __restrict__ b, float* __restrict__ out, int n)
{
    constexpr int FG = F / 4;
    long long idx = (long long)blockIdx.x * 256 + threadIdx.x;
    if (idx >= (long long)n * FG) return;
    int node = (int)(idx / FG);
    int fg = (int)(idx - (long long)node * FG);
    const int bf = fg * 4;

    const unsigned short* hs = (const unsigned short*)hh;
    auto lo16 = [](unsigned u) { return __uint_as_float(u << 16); };
    auto hi16 = [](unsigned u) { return __uint_as_float(u & 0xFFFF0000u); };

    uint2 su = *reinterpret_cast<const uint2*>(&hs[(size_t)node * F + bf]);
    float a0 = lo16(su.x), a1 = hi16(su.x), a2 = lo16(su.y), a3 = hi16(su.y);
    float c0 = 0.f, c1 = 0.f, c2 = 0.f, c3 = 0.f;

    int e = row_ptr[node];
    const int e1 = row_ptr[node + 1];
    for (; e + 4 <= e1; e += 4) {
        int s0 = csr[e], s1 = csr[e + 1], s2 = csr[e + 2], s3 = csr[e + 3];
        uint2 u0 = *reinterpret_cast<const uint2*>(&hs[(size_t)s0 * F + bf]);
        uint2 u1 = *reinterpret_cast<const uint2*>(&hs[(size_t)s1 * F + bf]);
        uint2 u2 = *reinterpret_cast<const uint2*>(&hs[(size_t)s2 * F + bf]);
        uint2 u3 = *reinterpret_cast<const uint2*>(&hs[(size_t)s3 * F + bf]);
        a0 += lo16(u0.x); a1 += hi16(u0.x); a2 += lo16(u0.y); a3 += hi16(u0.y);
        c0 += lo16(u1.x); c1 += hi16(u1.x); c2 += lo16(u1.y); c3 += hi16(u1.y);
        a0 += lo16(u2.x); a1 += hi16(u2.x); a2 += lo16(u2.y); a3 += hi16(u2.y);
        c0 += lo16(u3.x); c1 += hi16(u3.x); c2 += lo16(u3.y); c3 += hi16(u3.y);
    }
    for (; e < e1; ++e) {
        int s = csr[e];
        uint2 u = *reinterpret_cast<const uint2*>(&hs[(size_t)s * F + bf]);
        a0 += lo16(u.x); a1 += hi16(u.x); a2 += lo16(u.y); a3 += hi16(u.y);
    }
    a0 += c0; a1 += c1; a2 += c2; a3 += c3;

    float d = dis[node];
    float4 bb = *reinterpret_cast<const float4*>(&b[bf]);
    float4 o;
    o.x = fmaxf(fmaf(d, a0, bb.x), 0.0f);
    o.y = fmaxf(fmaf(d, a1, bb.y), 0.0f);
    o.z = fmaxf(fmaf(d, a2, bb.z), 0.0f);
    o.w = fmaxf(fmaf(d, a3, bb.w), 0.0f);
    *reinterpret_cast<float4*>(&out[(size_t)node * F + bf]) = o;
}

// ---------------- pooling ----------------

__global__ __launch_bounds__(256) void pool2_k(
    const float* __restrict__ h, const int* __restrict__ batch,
    float* __restrict__ sums, float* __restrict__ cnt, int n)
{
    constexpr int CHUNK = 1024;
    __shared__ float s[64 * 32];
    __shared__ float sc[64];
    for (int i = threadIdx.x; i < 64 * 32; i += 256) s[i] = 0.0f;
    if (threadIdx.x < 64) sc[threadIdx.x] = 0.0f;
    __syncthreads();

    long long start = (long long)blockIdx.x * CHUNK;
    long long end = start + CHUNK < n ? start + CHUNK : n;
    int total = (int)(end - start) * 32;
    for (int i = threadIdx.x; i < total; i += 256) {
        int r = i >> 5;
        int f = i & 31;
        int node = (int)start + r;
        int g = batch[node];
        atomicAdd(&s[g * 32 + f], h[(size_t)node * 32 + f]);
        if (f == 0) atomicAdd(&sc[g], 1.0f);
    }
    __syncthreads();
    for (int i = threadIdx.x; i < 64 * 32; i += 256) {
        float v = s[i];
        if (v != 0.0f) atomicAdd(&sums[i], v);
    }
    if (threadIdx.x < 64) {
        float v = sc[threadIdx.x];
        if (v != 0.0f) atomicAdd(&cnt[threadIdx.x], v);
    }
}

__global__ void head_k(const float* __restrict__ sums, const float* __restrict__ cnt,
                       const float* __restrict__ Wl, const float* __restrict__ bl,
                       float* __restrict__ out)
{
    int tid = threadIdx.x;
    if (tid < 128) {
        int g = tid >> 1;
        int o = tid & 1;
        float c = fmaxf(cnt[g], 1.0f);
        float a = 0.0f;
#pragma unroll
        for (int f = 0; f < 32; ++f)
            a += (sums[g * 32 + f] / c) * Wl[f * 2 + o];
        out[tid] = a + bl[o];
    }
}

// ---------------- launch ----------------

extern "C" void kernel_launch(void* const* d_in, const int* in_sizes, int n_in,
                              void* d_out, int out_size, void* d_ws, size_t ws_size,
                              hipStream_t stream)
{
    const float* x   = (const float*)d_in[0];
    const int*   ei  = (const int*)d_in[1];
    const int*   bat = (const int*)d_in[2];
    const float* W1  = (const float*)d_in[3];
    const float* b1  = (const float*)d_in[4];
    const float* W2  = (const float*)d_in[5];
    const float* b2  = (const float*)d_in[6];
    const float* W3  = (const float*)d_in[7];
    const float* b3  = (const float*)d_in[8];
    const float* Wl  = (const float*)d_in[9];
    const float* bl  = (const float*)d_in[10];

    const int N = in_sizes[0] / 128;
    const int E = in_sizes[1] / 2;
    const int* src = ei;
    const int* dst = ei + E;

    const int NB = (N + 255) >> 8;   // buckets of 256 nodes (<= 512 supported)
    const int G  = 128;              // blocks in bucket hist/scatter
    const int NBG = NB * G;

    char* ws = (char*)d_ws;
    size_t off = 0;
    auto alloc = [&](size_t bytes) -> char* {
        char* p = ws + off;
        off += (bytes + 255) & ~(size_t)255;
        return p;
    };
    float* dis     = (float*)alloc((size_t)N * 4);
    int*   row_ptr = (int*)  alloc((size_t)(N + 1) * 4);
    int*   bsum    = (int*)  alloc(256 * 4);
    int*   csr     = (int*)  alloc((size_t)E * 4);
    int*   T       = (int*)  alloc((size_t)NBG * 4);
    int*   Tsc     = (int*)  alloc((size_t)(NBG + 1) * 4);
    __hip_bfloat16* A = (__hip_bfloat16*)alloc((size_t)N * 84 * 2); // bf16 hh
    float* B       = (float*)alloc((size_t)N * 84 * 4); // layer outputs 1,3
    float* C       = (float*)alloc((size_t)N * 64 * 4); // layer output 2
    float* D       = (float*)alloc((size_t)(64 * 32 + 64) * 4);
    uint2* pairs   = (uint2*)C;  // overlay: pairs (E*8 B) used only in prologue

    dim3 blk(256);
    auto cdiv = [](long long a, long long b) { return (int)((a + b - 1) / b); };

    // ---- bucketed CSR build (no global atomics) ----
    bucket_hist_k<<<G, blk, 0, stream>>>(dst, T, E, NB);
    int nb_scan = cdiv(NBG, 2048);
    scan_block_k<<<nb_scan, blk, 0, stream>>>(T, Tsc, bsum, NBG);
    scan_partials_k<<<1, 64, 0, stream>>>(bsum, nb_scan);
    scan_add_k<<<cdiv(NBG, 256), blk, 0, stream>>>(Tsc, bsum, NBG, E);
    bucket_scatter_k<<<G, blk, 0, stream>>>(src, dst, Tsc, pairs, E, NB);
    bucket_csr_k<<<NB, blk, 0, stream>>>(pairs, Tsc, row_ptr, dis, csr, N, E, NB, G);

    // Layer 1: 128 -> 84
    gemm_scale_v2<128, 84, 48><<<cdiv(N, 48), blk, 0, stream>>>(x, W1, dis, A, N);
    aggregate_v2<84><<<cdiv((long long)N * 21, 256), blk, 0, stream>>>(A, row_ptr, csr, dis, b1, B, N);

    // Layer 2: 84 -> 64
    gemm_scale_v2<84, 64, 64><<<cdiv(N, 64), blk, 0, stream>>>(B, W2, dis, A, N);
    aggregate_v2<64><<<cdiv((long long)N * 16, 256), blk, 0, stream>>>(A, row_ptr, csr, dis, b2, C, N);

    // Layer 3: 64 -> 32
    gemm_scale_v2<64, 32, 128><<<cdiv(N, 128), blk, 0, stream>>>(C, W3, dis, A, N);
    aggregate_v2<32><<<cdiv((long long)N * 8, 256), blk, 0, stream>>>(A, row_ptr, csr, dis, b3, B, N);

    // global mean pool + head
    zero_k<<<cdiv(64 * 32 + 64, 256), blk, 0, stream>>>(D, 64 * 32 + 64);
    pool2_k<<<cdiv(N, 1024), blk, 0, stream>>>(B, bat, D, D + 64 * 32, N);
    head_k<<<1, 128, 0, stream>>>(D, D + 64 * 32, Wl, bl, (float*)d_out);
}

// Round 11
// 329.058 us; speedup vs baseline: 6.8967x; 1.0226x over previous
//
#include <hip/hip_runtime.h>
#include <hip/hip_bf16.h>

// ---------------- utility ----------------

__global__ void zero_k(float* __restrict__ p, int n) {
    for (int i = blockIdx.x * blockDim.x + threadIdx.x; i < n;
         i += gridDim.x * blockDim.x)
        p[i] = 0.0f;
}

// ---------------- bucketed CSR build (no global atomics) ----------------
// bucket = dst >> 8 (256 nodes/bucket). NB <= 512 supported.

__global__ __launch_bounds__(256) void bucket_hist_k(
    const int* __restrict__ dst, int* __restrict__ T, int E, int NB)
{
    __shared__ int hist[512];
    for (int b = threadIdx.x; b < NB; b += 256) hist[b] = 0;
    __syncthreads();
    int per = (E + gridDim.x - 1) / gridDim.x;
    int s = blockIdx.x * per;
    int e = min(E, s + per);
    for (int i = s + threadIdx.x; i < e; i += 256)
        atomicAdd(&hist[dst[i] >> 8], 1);
    __syncthreads();
    for (int b = threadIdx.x; b < NB; b += 256)
        T[b * gridDim.x + blockIdx.x] = hist[b];
}

// exclusive scan, 2048 elements per block (256 thr x 8)
__global__ __launch_bounds__(256) void scan_block_k(
    const int* __restrict__ in, int* __restrict__ out,
    int* __restrict__ bsum, int n)
{
    __shared__ int ts[256];
    int base = blockIdx.x * 2048;
    int i0 = base + threadIdx.x * 8;
    int vals[8];
    int s = 0;
#pragma unroll
    for (int j = 0; j < 8; ++j) {
        int v = (i0 + j) < n ? in[i0 + j] : 0;
        vals[j] = v; s += v;
    }
    ts[threadIdx.x] = s;
    __syncthreads();
    for (int d = 1; d < 256; d <<= 1) {
        int t = (threadIdx.x >= (unsigned)d) ? ts[threadIdx.x - d] : 0;
        __syncthreads();
        ts[threadIdx.x] += t;
        __syncthreads();
    }
    int run = ts[threadIdx.x] - s;
    if (threadIdx.x == 255) bsum[blockIdx.x] = ts[255];
#pragma unroll
    for (int j = 0; j < 8; ++j) {
        if (i0 + j < n) out[i0 + j] = run;
        run += vals[j];
    }
}

__global__ void scan_partials_k(int* __restrict__ bsum, int nb) {
    if (threadIdx.x == 0 && blockIdx.x == 0) {
        int run = 0;
        for (int i = 0; i < nb; ++i) { int t = bsum[i]; bsum[i] = run; run += t; }
    }
}

__global__ void scan_add_k(int* __restrict__ rp, const int* __restrict__ bsum,
                           int n, int E)
{
    int i = blockIdx.x * blockDim.x + threadIdx.x;
    if (i < n) rp[i] += bsum[i >> 11];
    if (i == 0) rp[n] = E;
}

__global__ __launch_bounds__(256) void bucket_scatter_k(
    const int* __restrict__ src, const int* __restrict__ dst,
    const int* __restrict__ Tsc, uint2* __restrict__ pairs, int E, int NB)
{
    __shared__ int cur[512];
    for (int b = threadIdx.x; b < NB; b += 256)
        cur[b] = Tsc[b * gridDim.x + blockIdx.x];
    __syncthreads();
    int per = (E + gridDim.x - 1) / gridDim.x;
    int s = blockIdx.x * per;
    int e = min(E, s + per);
    for (int i = s + threadIdx.x; i < e; i += 256) {
        int d = dst[i];
        int pos = atomicAdd(&cur[d >> 8], 1);
        pairs[pos] = make_uint2((unsigned)d, (unsigned)src[i]);
    }
}

// per-bucket: count -> LDS scan -> row_ptr + dis + csr fill (all LDS atomics)
__global__ __launch_bounds__(256) void bucket_csr_k(
    const uint2* __restrict__ pairs, const int* __restrict__ Tsc,
    int* __restrict__ row_ptr, float* __restrict__ dis,
    int* __restrict__ csr, int N, int E, int NB, int G)
{
    __shared__ int cnt[256];
    __shared__ int ts[256];
    __shared__ int cur[256];
    const int b = blockIdx.x;
    const int node0 = b << 8;
    const int e0 = Tsc[b * G];
    const int e1 = Tsc[(b + 1) * G];  // b==NB-1 reads Tsc[NB*G] == E
    const int j = threadIdx.x;
    cnt[j] = 0;
    __syncthreads();
    for (int i = e0 + j; i < e1; i += 256)
        atomicAdd(&cnt[pairs[i].x & 255u], 1);
    __syncthreads();
    int c = cnt[j];
    ts[j] = c;
    __syncthreads();
    for (int d = 1; d < 256; d <<= 1) {
        int t = (j >= d) ? ts[j - d] : 0;
        __syncthreads();
        ts[j] += t;
        __syncthreads();
    }
    int excl = ts[j] - c;
    int node = node0 + j;
    if (node < N) {
        row_ptr[node] = e0 + excl;
        dis[node] = rsqrtf(1.0f + (float)c);
    }
    cur[j] = e0 + excl;
    if (b == NB - 1 && j == 0) row_ptr[N] = E;
    __syncthreads();
    for (int i = e0 + j; i < e1; i += 256) {
        uint2 p = pairs[i];
        int pos = atomicAdd(&cur[p.x & 255u], 1);
        csr[pos] = (int)p.y;
    }
}

// ---------------- GEMM v3: K-chunked LDS, 4x4 register-blocked ----------------
// hh[i][f] = bf16( (in[i]@W)[f] * dis[i] ).  LDS holds only a KT-slice of W and x
// per step -> ~17KB LDS -> occupancy VGPR-bound (~60%) instead of LDS-bound (17%).

template<int FIN, int FOUT, int TILE_R, int KT>
__global__ __launch_bounds__(256) void gemm_scale_v3(
    const float* __restrict__ in, const float* __restrict__ W,
    const float* __restrict__ dis, __hip_bfloat16* __restrict__ hh, int n)
{
    constexpr int RG = TILE_R / 4;
    constexpr int CG = FOUT / 4;
    constexpr int NMT = RG * CG;
    constexpr int NKC = FIN / KT;
    static_assert(NMT <= 256, "tile too big");
    static_assert((RG & 3) == 0, "swizzle needs RG multiple of 4");
    static_assert(FIN % KT == 0 && (KT & 3) == 0, "KT must divide FIN, mult of 4");
    constexpr int SR = TILE_R + 4;
    __shared__ float Ws[KT * FOUT];
    __shared__ float xs[KT * SR];

    const int tid = threadIdx.x;
    const int rg = tid / CG;
    const int cg = tid - rg * CG;
    const bool active = tid < NMT;

    for (long long base = (long long)blockIdx.x * TILE_R; base < n;
         base += (long long)gridDim.x * TILE_R) {
        const int cnt = (int)((n - base) < TILE_R ? (n - base) : TILE_R);
        float acc[4][4];
#pragma unroll
        for (int i = 0; i < 4; ++i)
#pragma unroll
            for (int j = 0; j < 4; ++j) acc[i][j] = 0.f;

        for (int kk = 0; kk < NKC; ++kk) {
            __syncthreads();  // previous chunk's compute done
            for (int i = tid; i < KT * FOUT; i += 256)
                Ws[i] = W[kk * KT * FOUT + i];
            for (int i = tid; i < TILE_R * (KT / 4); i += 256) {
                int r  = i / (KT / 4);
                int c4 = i - r * (KT / 4);
                float4 v;
                if (r < cnt)
                    v = *reinterpret_cast<const float4*>(
                        &in[(base + r) * FIN + kk * KT + c4 * 4]);
                else
                    v = make_float4(0.f, 0.f, 0.f, 0.f);
                int gph = (((r >> 2) ^ (c4 & 3)) << 2) + (r & 3);
                float* p = &xs[(c4 * 4) * SR + gph];
                p[0]      = v.x;
                p[SR]     = v.y;
                p[2 * SR] = v.z;
                p[3 * SR] = v.w;
            }
            __syncthreads();
            if (active) {
#pragma unroll 8
                for (int k = 0; k < KT; ++k) {
                    float4 xa = *reinterpret_cast<const float4*>(
                        &xs[k * SR + ((rg ^ ((k >> 2) & 3)) << 2)]);
                    float4 wb = *reinterpret_cast<const float4*>(&Ws[k * FOUT + cg * 4]);
                    acc[0][0] = fmaf(xa.x, wb.x, acc[0][0]);
                    acc[0][1] = fmaf(xa.x, wb.y, acc[0][1]);
                    acc[0][2] = fmaf(xa.x, wb.z, acc[0][2]);
                    acc[0][3] = fmaf(xa.x, wb.w, acc[0][3]);
                    acc[1][0] = fmaf(xa.y, wb.x, acc[1][0]);
                    acc[1][1] = fmaf(xa.y, wb.y, acc[1][1]);
                    acc[1][2] = fmaf(xa.y, wb.z, acc[1][2]);
                    acc[1][3] = fmaf(xa.y, wb.w, acc[1][3]);
                    acc[2][0] = fmaf(xa.z, wb.x, acc[2][0]);
                    acc[2][1] = fmaf(xa.z, wb.y, acc[2][1]);
                    acc[2][2] = fmaf(xa.z, wb.z, acc[2][2]);
                    acc[2][3] = fmaf(xa.z, wb.w, acc[2][3]);
                    acc[3][0] = fmaf(xa.w, wb.x, acc[3][0]);
                    acc[3][1] = fmaf(xa.w, wb.y, acc[3][1]);
                    acc[3][2] = fmaf(xa.w, wb.z, acc[3][2]);
                    acc[3][3] = fmaf(xa.w, wb.w, acc[3][3]);
                }
            }
        }
        if (active) {
#pragma unroll
            for (int i = 0; i < 4; ++i) {
                int r = rg * 4 + i;
                if (r < cnt) {
                    float d = dis[base + r];
                    alignas(8) __hip_bfloat16 o[4];
                    o[0] = __float2bfloat16(acc[i][0] * d);
                    o[1] = __float2bfloat16(acc[i][1] * d);
                    o[2] = __float2bfloat16(acc[i][2] * d);
                    o[3] = __float2bfloat16(acc[i][3] * d);
                    *reinterpret_cast<uint2*>(
                        &hh[(size_t)(base + r) * FOUT + cg * 4]) =
                        *reinterpret_cast<const uint2*>(o);
                }
            }
        }
    }
}

// ---------------- CSR aggregate v3: uint2 gathers, 8-deep MLP ----------------

template<int F>
__global__ __launch_bounds__(256) void aggregate_v3(
    const __hip_bfloat16* __restrict__ hh, const int* __restrict__ row_ptr,
    const int* __restrict__ csr, const float* __restrict__ dis,
    const float* __restrict__ b, float* __restrict__ out, int n)
{
    constexpr int FG = F / 4;
    long long idx = (long long)blockIdx.x * 256 + threadIdx.x;
    if (idx >= (long long)n * FG) return;
    int node = (int)(idx / FG);
    int fg = (int)(idx - (long long)node * FG);
    const int bf = fg * 4;

    const unsigned short* hs = (const unsigned short*)hh;
    auto lo16 = [](unsigned u) { return __uint_as_float(u << 16); };
    auto hi16 = [](unsigned u) { return __uint_as_float(u & 0xFFFF0000u); };

    uint2 su = *reinterpret_cast<const uint2*>(&hs[(size_t)node * F + bf]);
    float a0 = lo16(su.x), a1 = hi16(su.x), a2 = lo16(su.y), a3 = hi16(su.y);
    float c0 = 0.f, c1 = 0.f, c2 = 0.f, c3 = 0.f;

    int e = row_ptr[node];
    const int e1 = row_ptr[node + 1];
    for (; e + 8 <= e1; e += 8) {
        int s0 = csr[e],     s1 = csr[e + 1], s2 = csr[e + 2], s3 = csr[e + 3];
        int s4 = csr[e + 4], s5 = csr[e + 5], s6 = csr[e + 6], s7 = csr[e + 7];
        uint2 u0 = *reinterpret_cast<const uint2*>(&hs[(size_t)s0 * F + bf]);
        uint2 u1 = *reinterpret_cast<const uint2*>(&hs[(size_t)s1 * F + bf]);
        uint2 u2 = *reinterpret_cast<const uint2*>(&hs[(size_t)s2 * F + bf]);
        uint2 u3 = *reinterpret_cast<const uint2*>(&hs[(size_t)s3 * F + bf]);
        uint2 u4 = *reinterpret_cast<const uint2*>(&hs[(size_t)s4 * F + bf]);
        uint2 u5 = *reinterpret_cast<const uint2*>(&hs[(size_t)s5 * F + bf]);
        uint2 u6 = *reinterpret_cast<const uint2*>(&hs[(size_t)s6 * F + bf]);
        uint2 u7 = *reinterpret_cast<const uint2*>(&hs[(size_t)s7 * F + bf]);
        a0 += lo16(u0.x); a1 += hi16(u0.x); a2 += lo16(u0.y); a3 += hi16(u0.y);
        c0 += lo16(u1.x); c1 += hi16(u1.x); c2 += lo16(u1.y); c3 += hi16(u1.y);
        a0 += lo16(u2.x); a1 += hi16(u2.x); a2 += lo16(u2.y); a3 += hi16(u2.y);
        c0 += lo16(u3.x); c1 += hi16(u3.x); c2 += lo16(u3.y); c3 += hi16(u3.y);
        a0 += lo16(u4.x); a1 += hi16(u4.x); a2 += lo16(u4.y); a3 += hi16(u4.y);
        c0 += lo16(u5.x); c1 += hi16(u5.x); c2 += lo16(u5.y); c3 += hi16(u5.y);
        a0 += lo16(u6.x); a1 += hi16(u6.x); a2 += lo16(u6.y); a3 += hi16(u6.y);
        c0 += lo16(u7.x); c1 += hi16(u7.x); c2 += lo16(u7.y); c3 += hi16(u7.y);
    }
    if (e + 4 <= e1) {
        int s0 = csr[e], s1 = csr[e + 1], s2 = csr[e + 2], s3 = csr[e + 3];
        uint2 u0 = *reinterpret_cast<const uint2*>(&hs[(size_t)s0 * F + bf]);
        uint2 u1 = *reinterpret_cast<const uint2*>(&hs[(size_t)s1 * F + bf]);
        uint2 u2 = *reinterpret_cast<const uint2*>(&hs[(size_t)s2 * F + bf]);
        uint2 u3 = *reinterpret_cast<const uint2*>(&hs[(size_t)s3 * F + bf]);
        a0 += lo16(u0.x); a1 += hi16(u0.x); a2 += lo16(u0.y); a3 += hi16(u0.y);
        c0 += lo16(u1.x); c1 += hi16(u1.x); c2 += lo16(u1.y); c3 += hi16(u1.y);
        a0 += lo16(u2.x); a1 += hi16(u2.x); a2 += lo16(u2.y); a3 += hi16(u2.y);
        c0 += lo16(u3.x); c1 += hi16(u3.x); c2 += lo16(u3.y); c3 += hi16(u3.y);
        e += 4;
    }
    for (; e < e1; ++e) {
        int s = csr[e];
        uint2 u = *reinterpret_cast<const uint2*>(&hs[(size_t)s * F + bf]);
        a0 += lo16(u.x); a1 += hi16(u.x); a2 += lo16(u.y); a3 += hi16(u.y);
    }
    a0 += c0; a1 += c1; a2 += c2; a3 += c3;

    float d = dis[node];
    float4 bb = *reinterpret_cast<const float4*>(&b[bf]);
    float4 o;
    o.x = fmaxf(fmaf(d, a0, bb.x), 0.0f);
    o.y = fmaxf(fmaf(d, a1, bb.y), 0.0f);
    o.z = fmaxf(fmaf(d, a2, bb.z), 0.0f);
    o.w = fmaxf(fmaf(d, a3, bb.w), 0.0f);
    *reinterpret_cast<float4*>(&out[(size_t)node * F + bf]) = o;
}

// ---------------- pooling ----------------

__global__ __launch_bounds__(256) void pool2_k(
    const float* __restrict__ h, const int* __restrict__ batch,
    float* __restrict__ sums, float* __restrict__ cnt, int n)
{
    constexpr int CHUNK = 1024;
    __shared__ float s[64 * 32];
    __shared__ float sc[64];
    for (int i = threadIdx.x; i < 64 * 32; i += 256) s[i] = 0.0f;
    if (threadIdx.x < 64) sc[threadIdx.x] = 0.0f;
    __syncthreads();

    long long start = (long long)blockIdx.x * CHUNK;
    long long end = start + CHUNK < n ? start + CHUNK : n;
    int total = (int)(end - start) * 32;
    for (int i = threadIdx.x; i < total; i += 256) {
        int r = i >> 5;
        int f = i & 31;
        int node = (int)start + r;
        int g = batch[node];
        atomicAdd(&s[g * 32 + f], h[(size_t)node * 32 + f]);
        if (f == 0) atomicAdd(&sc[g], 1.0f);
    }
    __syncthreads();
    for (int i = threadIdx.x; i < 64 * 32; i += 256) {
        float v = s[i];
        if (v != 0.0f) atomicAdd(&sums[i], v);
    }
    if (threadIdx.x < 64) {
        float v = sc[threadIdx.x];
        if (v != 0.0f) atomicAdd(&cnt[threadIdx.x], v);
    }
}

__global__ void head_k(const float* __restrict__ sums, const float* __restrict__ cnt,
                       const float* __restrict__ Wl, const float* __restrict__ bl,
                       float* __restrict__ out)
{
    int tid = threadIdx.x;
    if (tid < 128) {
        int g = tid >> 1;
        int o = tid & 1;
        float c = fmaxf(cnt[g], 1.0f);
        float a = 0.0f;
#pragma unroll
        for (int f = 0; f < 32; ++f)
            a += (sums[g * 32 + f] / c) * Wl[f * 2 + o];
        out[tid] = a + bl[o];
    }
}

// ---------------- launch ----------------

extern "C" void kernel_launch(void* const* d_in, const int* in_sizes, int n_in,
                              void* d_out, int out_size, void* d_ws, size_t ws_size,
                              hipStream_t stream)
{
    const float* x   = (const float*)d_in[0];
    const int*   ei  = (const int*)d_in[1];
    const int*   bat = (const int*)d_in[2];
    const float* W1  = (const float*)d_in[3];
    const float* b1  = (const float*)d_in[4];
    const float* W2  = (const float*)d_in[5];
    const float* b2  = (const float*)d_in[6];
    const float* W3  = (const float*)d_in[7];
    const float* b3  = (const float*)d_in[8];
    const float* Wl  = (const float*)d_in[9];
    const float* bl  = (const float*)d_in[10];

    const int N = in_sizes[0] / 128;
    const int E = in_sizes[1] / 2;
    const int* src = ei;
    const int* dst = ei + E;

    const int NB = (N + 255) >> 8;   // buckets of 256 nodes (<= 512 supported)
    const int G  = 128;              // blocks in bucket hist/scatter
    const int NBG = NB * G;

    char* ws = (char*)d_ws;
    size_t off = 0;
    auto alloc = [&](size_t bytes) -> char* {
        char* p = ws + off;
        off += (bytes + 255) & ~(size_t)255;
        return p;
    };
    float* dis     = (float*)alloc((size_t)N * 4);
    int*   row_ptr = (int*)  alloc((size_t)(N + 1) * 4);
    int*   bsum    = (int*)  alloc(256 * 4);
    int*   csr     = (int*)  alloc((size_t)E * 4);
    int*   T       = (int*)  alloc((size_t)NBG * 4);
    int*   Tsc     = (int*)  alloc((size_t)(NBG + 1) * 4);
    __hip_bfloat16* A = (__hip_bfloat16*)alloc((size_t)N * 84 * 2); // bf16 hh
    float* B       = (float*)alloc((size_t)N * 84 * 4); // layer outputs 1,3
    float* C       = (float*)alloc((size_t)N * 64 * 4); // layer output 2
    float* D       = (float*)alloc((size_t)(64 * 32 + 64) * 4);
    uint2* pairs   = (uint2*)C;  // overlay: pairs (E*8 B) used only in prologue

    dim3 blk(256);
    auto cdiv = [](long long a, long long b) { return (int)((a + b - 1) / b); };

    // ---- bucketed CSR build (no global atomics) ----
    bucket_hist_k<<<G, blk, 0, stream>>>(dst, T, E, NB);
    int nb_scan = cdiv(NBG, 2048);
    scan_block_k<<<nb_scan, blk, 0, stream>>>(T, Tsc, bsum, NBG);
    scan_partials_k<<<1, 64, 0, stream>>>(bsum, nb_scan);
    scan_add_k<<<cdiv(NBG, 256), blk, 0, stream>>>(Tsc, bsum, NBG, E);
    bucket_scatter_k<<<G, blk, 0, stream>>>(src, dst, Tsc, pairs, E, NB);
    bucket_csr_k<<<NB, blk, 0, stream>>>(pairs, Tsc, row_ptr, dis, csr, N, E, NB, G);

    // Layer 1: 128 -> 84
    gemm_scale_v3<128, 84, 48, 32><<<cdiv(N, 48), blk, 0, stream>>>(x, W1, dis, A, N);
    aggregate_v3<84><<<cdiv((long long)N * 21, 256), blk, 0, stream>>>(A, row_ptr, csr, dis, b1, B, N);

    // Layer 2: 84 -> 64
    gemm_scale_v3<84, 64, 64, 28><<<cdiv(N, 64), blk, 0, stream>>>(B, W2, dis, A, N);
    aggregate_v3<64><<<cdiv((long long)N * 16, 256), blk, 0, stream>>>(A, row_ptr, csr, dis, b2, C, N);

    // Layer 3: 64 -> 32
    gemm_scale_v3<64, 32, 128, 32><<<cdiv(N, 128), blk, 0, stream>>>(C, W3, dis, A, N);
    aggregate_v3<32><<<cdiv((long long)N * 8, 256), blk, 0, stream>>>(A, row_ptr, csr, dis, b3, B, N);

    // global mean pool + head
    zero_k<<<cdiv(64 * 32 + 64, 256), blk, 0, stream>>>(D, 64 * 32 + 64);
    pool2_k<<<cdiv(N, 1024), blk, 0, stream>>>(B, bat, D, D + 64 * 32, N);
    head_k<<<1, 128, 0, stream>>>(D, D + 64 * 32, Wl, bl, (float*)d_out);
}

// Round 13
// 327.324 us; speedup vs baseline: 6.9332x; 1.0053x over previous
//
#include <hip/hip_runtime.h>
#include <hip/hip_bf16.h>

typedef __attribute__((ext_vector_type(8))) short bf16x8;
typedef __attribute__((ext_vector_type(4))) float f32x4;

__device__ inline short f2bf(float f) {
    __hip_bfloat16 h = __float2bfloat16(f);
    return *reinterpret_cast<short*>(&h);
}

// ---------------- utility ----------------

__global__ void zero_k(float* __restrict__ p, int n) {
    for (int i = blockIdx.x * blockDim.x + threadIdx.x; i < n;
         i += gridDim.x * blockDim.x)
        p[i] = 0.0f;
}

// ---------------- bucketed CSR build (no global atomics) ----------------

__global__ __launch_bounds__(256) void bucket_hist_k(
    const int* __restrict__ dst, int* __restrict__ T, int E, int NB)
{
    __shared__ int hist[512];
    for (int b = threadIdx.x; b < NB; b += 256) hist[b] = 0;
    __syncthreads();
    int per = (E + gridDim.x - 1) / gridDim.x;
    int s = blockIdx.x * per;
    int e = min(E, s + per);
    for (int i = s + threadIdx.x; i < e; i += 256)
        atomicAdd(&hist[dst[i] >> 8], 1);
    __syncthreads();
    for (int b = threadIdx.x; b < NB; b += 256)
        T[b * gridDim.x + blockIdx.x] = hist[b];
}

__global__ __launch_bounds__(256) void scan_block_k(
    const int* __restrict__ in, int* __restrict__ out,
    int* __restrict__ bsum, int n)
{
    __shared__ int ts[256];
    int base = blockIdx.x * 2048;
    int i0 = base + threadIdx.x * 8;
    int vals[8];
    int s = 0;
#pragma unroll
    for (int j = 0; j < 8; ++j) {
        int v = (i0 + j) < n ? in[i0 + j] : 0;
        vals[j] = v; s += v;
    }
    ts[threadIdx.x] = s;
    __syncthreads();
    for (int d = 1; d < 256; d <<= 1) {
        int t = (threadIdx.x >= (unsigned)d) ? ts[threadIdx.x - d] : 0;
        __syncthreads();
        ts[threadIdx.x] += t;
        __syncthreads();
    }
    int run = ts[threadIdx.x] - s;
    if (threadIdx.x == 255) bsum[blockIdx.x] = ts[255];
#pragma unroll
    for (int j = 0; j < 8; ++j) {
        if (i0 + j < n) out[i0 + j] = run;
        run += vals[j];
    }
}

__global__ void scan_partials_k(int* __restrict__ bsum, int nb) {
    if (threadIdx.x == 0 && blockIdx.x == 0) {
        int run = 0;
        for (int i = 0; i < nb; ++i) { int t = bsum[i]; bsum[i] = run; run += t; }
    }
}

__global__ void scan_add_k(int* __restrict__ rp, const int* __restrict__ bsum,
                           int n, int E)
{
    int i = blockIdx.x * blockDim.x + threadIdx.x;
    if (i < n) rp[i] += bsum[i >> 11];
    if (i == 0) rp[n] = E;
}

__global__ __launch_bounds__(256) void bucket_scatter_k(
    const int* __restrict__ src, const int* __restrict__ dst,
    const int* __restrict__ Tsc, uint2* __restrict__ pairs, int E, int NB)
{
    __shared__ int cur[512];
    for (int b = threadIdx.x; b < NB; b += 256)
        cur[b] = Tsc[b * gridDim.x + blockIdx.x];
    __syncthreads();
    int per = (E + gridDim.x - 1) / gridDim.x;
    int s = blockIdx.x * per;
    int e = min(E, s + per);
    for (int i = s + threadIdx.x; i < e; i += 256) {
        int d = dst[i];
        int pos = atomicAdd(&cur[d >> 8], 1);
        pairs[pos] = make_uint2((unsigned)d, (unsigned)src[i]);
    }
}

__global__ __launch_bounds__(256) void bucket_csr_k(
    const uint2* __restrict__ pairs, const int* __restrict__ Tsc,
    int* __restrict__ row_ptr, float* __restrict__ dis,
    int* __restrict__ csr, int N, int E, int NB, int G)
{
    __shared__ int cnt[256];
    __shared__ int ts[256];
    __shared__ int cur[256];
    const int b = blockIdx.x;
    const int node0 = b << 8;
    const int e0 = Tsc[b * G];
    const int e1 = Tsc[(b + 1) * G];
    const int j = threadIdx.x;
    cnt[j] = 0;
    __syncthreads();
    for (int i = e0 + j; i < e1; i += 256)
        atomicAdd(&cnt[pairs[i].x & 255u], 1);
    __syncthreads();
    int c = cnt[j];
    ts[j] = c;
    __syncthreads();
    for (int d = 1; d < 256; d <<= 1) {
        int t = (j >= d) ? ts[j - d] : 0;
        __syncthreads();
        ts[j] += t;
        __syncthreads();
    }
    int excl = ts[j] - c;
    int node = node0 + j;
    if (node < N) {
        row_ptr[node] = e0 + excl;
        dis[node] = rsqrtf(1.0f + (float)c);
    }
    cur[j] = e0 + excl;
    if (b == NB - 1 && j == 0) row_ptr[N] = E;
    __syncthreads();
    for (int i = e0 + j; i < e1; i += 256) {
        uint2 p = pairs[i];
        int pos = atomicAdd(&cur[p.x & 255u], 1);
        csr[pos] = (int)p.y;
    }
}

// ---------------- GEMM v4: MFMA 16x16x32 bf16 ----------------
// hh[i][f] = bf16( (in[i]@W)[f] * dis[i] ), f32 MFMA accumulate.
// Block = 4 waves x 16 rows = 64 rows. LDS: xb[64][KP] bf16 (row-major,
// XOR-swizzled), wt[CT*16][KP] bf16 (W transposed [col][k], swizzled).
// Swizzle byte ^= (row&7)<<4 permutes 16B chunks; requires chunks/row
// (= KP/8) to be a multiple of 8 -> KP % 64 == 0 (KP=96 corrupts rows!).

template<int FIN, int FOUT, int KP, int CT>
__global__ __launch_bounds__(256) void gemm_mfma(
    const float* __restrict__ in, const float* __restrict__ W,
    const float* __restrict__ dis, __hip_bfloat16* __restrict__ hh, int n)
{
    constexpr int KP2 = KP * 2;
    constexpr int NKK = KP / 32;
    constexpr int CT16 = CT * 16;
    static_assert(FIN % 4 == 0 && KP % 32 == 0 && KP >= FIN, "");
    static_assert(KP % 64 == 0, "swizzle needs chunks/row multiple of 8");
    __shared__ __align__(16) short xb[64 * KP];
    __shared__ __align__(16) short wt[CT16 * KP];
    const int tid = threadIdx.x;
    const long long base = (long long)blockIdx.x * 64;
    const int cnt = (int)min((long long)64, (long long)n - base);

    // stage W transposed + bf16; zero-pad k>=FIN, col>=FOUT
    for (int i = tid; i < CT16 * KP; i += 256) {
        int col = i % CT16;
        int k   = i / CT16;
        short v = (k < FIN && col < FOUT) ? f2bf(W[k * FOUT + col]) : (short)0;
        *reinterpret_cast<short*>((char*)wt + col * KP2 +
                                  ((2 * k) ^ ((col & 7) << 4))) = v;
    }
    // stage x tile -> bf16, swizzled
    for (int i = tid; i < 64 * (KP / 4); i += 256) {
        int r  = i / (KP / 4);
        int k0 = (i - r * (KP / 4)) * 4;
        float4 v = make_float4(0.f, 0.f, 0.f, 0.f);
        if (r < cnt && k0 < FIN)
            v = *reinterpret_cast<const float4*>(&in[(base + r) * FIN + k0]);
        unsigned lo = (unsigned short)f2bf(v.x) | ((unsigned)(unsigned short)f2bf(v.y) << 16);
        unsigned hi = (unsigned short)f2bf(v.z) | ((unsigned)(unsigned short)f2bf(v.w) << 16);
        *reinterpret_cast<uint2*>((char*)xb + r * KP2 +
                                  ((k0 * 2) ^ ((r & 7) << 4))) = make_uint2(lo, hi);
    }
    __syncthreads();

    const int wv = tid >> 6, lane = tid & 63;
    const int rlo = lane & 15, kg = lane >> 4;
    const int kb = kg * 8;
    const int arow = wv * 16 + rlo;

    bf16x8 a[NKK];
#pragma unroll
    for (int kk = 0; kk < NKK; ++kk)
        a[kk] = *reinterpret_cast<const bf16x8*>(
            (const char*)xb + arow * KP2 + (((kk * 32 + kb) * 2) ^ ((arow & 7) << 4)));

    f32x4 acc[CT];
#pragma unroll
    for (int nn = 0; nn < CT; ++nn) acc[nn] = (f32x4){0.f, 0.f, 0.f, 0.f};

#pragma unroll
    for (int nn = 0; nn < CT; ++nn) {
        const int col = nn * 16 + rlo;
#pragma unroll
        for (int kk = 0; kk < NKK; ++kk) {
            bf16x8 b = *reinterpret_cast<const bf16x8*>(
                (const char*)wt + col * KP2 + (((kk * 32 + kb) * 2) ^ ((rlo & 7) << 4)));
            acc[nn] = __builtin_amdgcn_mfma_f32_16x16x32_bf16(a[kk], b, acc[nn], 0, 0, 0);
        }
    }

    // epilogue: scale by dis, bf16 store (D: row=(l>>4)*4+i, col=nn*16+(l&15))
    const int r0 = wv * 16 + kg * 4;
    float dv[4];
#pragma unroll
    for (int i = 0; i < 4; ++i)
        dv[i] = (r0 + i < cnt) ? dis[base + r0 + i] : 0.f;
#pragma unroll
    for (int nn = 0; nn < CT; ++nn) {
        const int col = nn * 16 + rlo;
        if (col < FOUT) {
#pragma unroll
            for (int i = 0; i < 4; ++i) {
                int r = r0 + i;
                if (r < cnt) {
                    __hip_bfloat16 o = __float2bfloat16(acc[nn][i] * dv[i]);
                    hh[(size_t)(base + r) * FOUT + col] = o;
                }
            }
        }
    }
}

// ---------------- CSR aggregate v3: uint2 gathers, 8-deep MLP ----------------

template<int F>
__global__ __launch_bounds__(256) void aggregate_v3(
    const __hip_bfloat16* __restrict__ hh, const int* __restrict__ row_ptr,
    const int* __restrict__ csr, const float* __restrict__ dis,
    const float* __restrict__ b, float* __restrict__ out, int n)
{
    constexpr int FG = F / 4;
    long long idx = (long long)blockIdx.x * 256 + threadIdx.x;
    if (idx >= (long long)n * FG) return;
    int node = (int)(idx / FG);
    int fg = (int)(idx - (long long)node * FG);
    const int bf = fg * 4;

    const unsigned short* hs = (const unsigned short*)hh;
    auto lo16 = [](unsigned u) { return __uint_as_float(u << 16); };
    auto hi16 = [](unsigned u) { return __uint_as_float(u & 0xFFFF0000u); };

    uint2 su = *reinterpret_cast<const uint2*>(&hs[(size_t)node * F + bf]);
    float a0 = lo16(su.x), a1 = hi16(su.x), a2 = lo16(su.y), a3 = hi16(su.y);
    float c0 = 0.f, c1 = 0.f, c2 = 0.f, c3 = 0.f;

    int e = row_ptr[node];
    const int e1 = row_ptr[node + 1];
    for (; e + 8 <= e1; e += 8) {
        int s0 = csr[e],     s1 = csr[e + 1], s2 = csr[e + 2], s3 = csr[e + 3];
        int s4 = csr[e + 4], s5 = csr[e + 5], s6 = csr[e + 6], s7 = csr[e + 7];
        uint2 u0 = *reinterpret_cast<const uint2*>(&hs[(size_t)s0 * F + bf]);
        uint2 u1 = *reinterpret_cast<const uint2*>(&hs[(size_t)s1 * F + bf]);
        uint2 u2 = *reinterpret_cast<const uint2*>(&hs[(size_t)s2 * F + bf]);
        uint2 u3 = *reinterpret_cast<const uint2*>(&hs[(size_t)s3 * F + bf]);
        uint2 u4 = *reinterpret_cast<const uint2*>(&hs[(size_t)s4 * F + bf]);
        uint2 u5 = *reinterpret_cast<const uint2*>(&hs[(size_t)s5 * F + bf]);
        uint2 u6 = *reinterpret_cast<const uint2*>(&hs[(size_t)s6 * F + bf]);
        uint2 u7 = *reinterpret_cast<const uint2*>(&hs[(size_t)s7 * F + bf]);
        a0 += lo16(u0.x); a1 += hi16(u0.x); a2 += lo16(u0.y); a3 += hi16(u0.y);
        c0 += lo16(u1.x); c1 += hi16(u1.x); c2 += lo16(u1.y); c3 += hi16(u1.y);
        a0 += lo16(u2.x); a1 += hi16(u2.x); a2 += lo16(u2.y); a3 += hi16(u2.y);
        c0 += lo16(u3.x); c1 += hi16(u3.x); c2 += lo16(u3.y); c3 += hi16(u3.y);
        a0 += lo16(u4.x); a1 += hi16(u4.x); a2 += lo16(u4.y); a3 += hi16(u4.y);
        c0 += lo16(u5.x); c1 += hi16(u5.x); c2 += lo16(u5.y); c3 += hi16(u5.y);
        a0 += lo16(u6.x); a1 += hi16(u6.x); a2 += lo16(u6.y); a3 += hi16(u6.y);
        c0 += lo16(u7.x); c1 += hi16(u7.x); c2 += lo16(u7.y); c3 += hi16(u7.y);
    }
    if (e + 4 <= e1) {
        int s0 = csr[e], s1 = csr[e + 1], s2 = csr[e + 2], s3 = csr[e + 3];
        uint2 u0 = *reinterpret_cast<const uint2*>(&hs[(size_t)s0 * F + bf]);
        uint2 u1 = *reinterpret_cast<const uint2*>(&hs[(size_t)s1 * F + bf]);
        uint2 u2 = *reinterpret_cast<const uint2*>(&hs[(size_t)s2 * F + bf]);
        uint2 u3 = *reinterpret_cast<const uint2*>(&hs[(size_t)s3 * F + bf]);
        a0 += lo16(u0.x); a1 += hi16(u0.x); a2 += lo16(u0.y); a3 += hi16(u0.y);
        c0 += lo16(u1.x); c1 += hi16(u1.x); c2 += lo16(u1.y); c3 += hi16(u1.y);
        a0 += lo16(u2.x); a1 += hi16(u2.x); a2 += lo16(u2.y); a3 += hi16(u2.y);
        c0 += lo16(u3.x); c1 += hi16(u3.x); c2 += lo16(u3.y); c3 += hi16(u3.y);
        e += 4;
    }
    for (; e < e1; ++e) {
        int s = csr[e];
        uint2 u = *reinterpret_cast<const uint2*>(&hs[(size_t)s * F + bf]);
        a0 += lo16(u.x); a1 += hi16(u.x); a2 += lo16(u.y); a3 += hi16(u.y);
    }
    a0 += c0; a1 += c1; a2 += c2; a3 += c3;

    float d = dis[node];
    float4 bb = *reinterpret_cast<const float4*>(&b[bf]);
    float4 o;
    o.x = fmaxf(fmaf(d, a0, bb.x), 0.0f);
    o.y = fmaxf(fmaf(d, a1, bb.y), 0.0f);
    o.z = fmaxf(fmaf(d, a2, bb.z), 0.0f);
    o.w = fmaxf(fmaf(d, a3, bb.w), 0.0f);
    *reinterpret_cast<float4*>(&out[(size_t)node * F + bf]) = o;
}

// ---------------- pooling ----------------

__global__ __launch_bounds__(256) void pool2_k(
    const float* __restrict__ h, const int* __restrict__ batch,
    float* __restrict__ sums, float* __restrict__ cnt, int n)
{
    constexpr int CHUNK = 1024;
    __shared__ float s[64 * 32];
    __shared__ float sc[64];
    for (int i = threadIdx.x; i < 64 * 32; i += 256) s[i] = 0.0f;
    if (threadIdx.x < 64) sc[threadIdx.x] = 0.0f;
    __syncthreads();

    long long start = (long long)blockIdx.x * CHUNK;
    long long end = start + CHUNK < n ? start + CHUNK : n;
    int total = (int)(end - start) * 32;
    for (int i = threadIdx.x; i < total; i += 256) {
        int r = i >> 5;
        int f = i & 31;
        int node = (int)start + r;
        int g = batch[node];
        atomicAdd(&s[g * 32 + f], h[(size_t)node * 32 + f]);
        if (f == 0) atomicAdd(&sc[g], 1.0f);
    }
    __syncthreads();
    for (int i = threadIdx.x; i < 64 * 32; i += 256) {
        float v = s[i];
        if (v != 0.0f) atomicAdd(&sums[i], v);
    }
    if (threadIdx.x < 64) {
        float v = sc[threadIdx.x];
        if (v != 0.0f) atomicAdd(&cnt[threadIdx.x], v);
    }
}

__global__ void head_k(const float* __restrict__ sums, const float* __restrict__ cnt,
                       const float* __restrict__ Wl, const float* __restrict__ bl,
                       float* __restrict__ out)
{
    int tid = threadIdx.x;
    if (tid < 128) {
        int g = tid >> 1;
        int o = tid & 1;
        float c = fmaxf(cnt[g], 1.0f);
        float a = 0.0f;
#pragma unroll
        for (int f = 0; f < 32; ++f)
            a += (sums[g * 32 + f] / c) * Wl[f * 2 + o];
        out[tid] = a + bl[o];
    }
}

// ---------------- launch ----------------

extern "C" void kernel_launch(void* const* d_in, const int* in_sizes, int n_in,
                              void* d_out, int out_size, void* d_ws, size_t ws_size,
                              hipStream_t stream)
{
    const float* x   = (const float*)d_in[0];
    const int*   ei  = (const int*)d_in[1];
    const int*   bat = (const int*)d_in[2];
    const float* W1  = (const float*)d_in[3];
    const float* b1  = (const float*)d_in[4];
    const float* W2  = (const float*)d_in[5];
    const float* b2  = (const float*)d_in[6];
    const float* W3  = (const float*)d_in[7];
    const float* b3  = (const float*)d_in[8];
    const float* Wl  = (const float*)d_in[9];
    const float* bl  = (const float*)d_in[10];

    const int N = in_sizes[0] / 128;
    const int E = in_sizes[1] / 2;
    const int* src = ei;
    const int* dst = ei + E;

    const int NB = (N + 255) >> 8;
    const int G  = 128;
    const int NBG = NB * G;

    char* ws = (char*)d_ws;
    size_t off = 0;
    auto alloc = [&](size_t bytes) -> char* {
        char* p = ws + off;
        off += (bytes + 255) & ~(size_t)255;
        return p;
    };
    float* dis     = (float*)alloc((size_t)N * 4);
    int*   row_ptr = (int*)  alloc((size_t)(N + 1) * 4);
    int*   bsum    = (int*)  alloc(256 * 4);
    int*   csr     = (int*)  alloc((size_t)E * 4);
    int*   T       = (int*)  alloc((size_t)NBG * 4);
    int*   Tsc     = (int*)  alloc((size_t)(NBG + 1) * 4);
    __hip_bfloat16* A = (__hip_bfloat16*)alloc((size_t)N * 84 * 2);
    float* B       = (float*)alloc((size_t)N * 84 * 4);
    float* C       = (float*)alloc((size_t)N * 64 * 4);
    float* D       = (float*)alloc((size_t)(64 * 32 + 64) * 4);
    uint2* pairs   = (uint2*)C;

    dim3 blk(256);
    auto cdiv = [](long long a, long long b) { return (int)((a + b - 1) / b); };

    // ---- bucketed CSR build ----
    bucket_hist_k<<<G, blk, 0, stream>>>(dst, T, E, NB);
    int nb_scan = cdiv(NBG, 2048);
    scan_block_k<<<nb_scan, blk, 0, stream>>>(T, Tsc, bsum, NBG);
    scan_partials_k<<<1, 64, 0, stream>>>(bsum, nb_scan);
    scan_add_k<<<cdiv(NBG, 256), blk, 0, stream>>>(Tsc, bsum, NBG, E);
    bucket_scatter_k<<<G, blk, 0, stream>>>(src, dst, Tsc, pairs, E, NB);
    bucket_csr_k<<<NB, blk, 0, stream>>>(pairs, Tsc, row_ptr, dis, csr, N, E, NB, G);

    // Layer 1: 128 -> 84   (KP=128, 6 col-tiles)
    gemm_mfma<128, 84, 128, 6><<<cdiv(N, 64), blk, 0, stream>>>(x, W1, dis, A, N);
    aggregate_v3<84><<<cdiv((long long)N * 21, 256), blk, 0, stream>>>(A, row_ptr, csr, dis, b1, B, N);

    // Layer 2: 84 -> 64    (KP=128: padded from 96 -- KP%64==0 required, 4 col-tiles)
    gemm_mfma<84, 64, 128, 4><<<cdiv(N, 64), blk, 0, stream>>>(B, W2, dis, A, N);
    aggregate_v3<64><<<cdiv((long long)N * 16, 256), blk, 0, stream>>>(A, row_ptr, csr, dis, b2, C, N);

    // Layer 3: 64 -> 32    (KP=64, 2 col-tiles)
    gemm_mfma<64, 32, 64, 2><<<cdiv(N, 64), blk, 0, stream>>>(C, W3, dis, A, N);
    aggregate_v3<32><<<cdiv((long long)N * 8, 256), blk, 0, stream>>>(A, row_ptr, csr, dis, b3, B, N);

    // global mean pool + head
    zero_k<<<cdiv(64 * 32 + 64, 256), blk, 0, stream>>>(D, 64 * 32 + 64);
    pool2_k<<<cdiv(N, 1024), blk, 0, stream>>>(B, bat, D, D + 64 * 32, N);
    head_k<<<1, 128, 0, stream>>>(D, D + 64 * 32, Wl, bl, (float*)d_out);
}

// Round 14
// 295.840 us; speedup vs baseline: 7.6711x; 1.1064x over previous
//
#include <hip/hip_runtime.h>
#include <hip/hip_bf16.h>

typedef __attribute__((ext_vector_type(8))) short bf16x8;
typedef __attribute__((ext_vector_type(4))) float f32x4;

__device__ inline short f2bf(float f) {
    __hip_bfloat16 h = __float2bfloat16(f);
    return *reinterpret_cast<short*>(&h);
}

// ---------------- utility ----------------

__global__ void zero_k(float* __restrict__ p, int n) {
    for (int i = blockIdx.x * blockDim.x + threadIdx.x; i < n;
         i += gridDim.x * blockDim.x)
        p[i] = 0.0f;
}

// ---------------- bucketed CSR build (no global atomics) ----------------

__global__ __launch_bounds__(256) void bucket_hist_k(
    const int* __restrict__ dst, int* __restrict__ T, int E, int NB)
{
    __shared__ int hist[512];
    for (int b = threadIdx.x; b < NB; b += 256) hist[b] = 0;
    __syncthreads();
    int per = (E + gridDim.x - 1) / gridDim.x;
    int s = blockIdx.x * per;
    int e = min(E, s + per);
    for (int i = s + threadIdx.x; i < e; i += 256)
        atomicAdd(&hist[dst[i] >> 8], 1);
    __syncthreads();
    for (int b = threadIdx.x; b < NB; b += 256)
        T[b * gridDim.x + blockIdx.x] = hist[b];
}

__global__ __launch_bounds__(256) void scan_block_k(
    const int* __restrict__ in, int* __restrict__ out,
    int* __restrict__ bsum, int n)
{
    __shared__ int ts[256];
    int base = blockIdx.x * 2048;
    int i0 = base + threadIdx.x * 8;
    int vals[8];
    int s = 0;
#pragma unroll
    for (int j = 0; j < 8; ++j) {
        int v = (i0 + j) < n ? in[i0 + j] : 0;
        vals[j] = v; s += v;
    }
    ts[threadIdx.x] = s;
    __syncthreads();
    for (int d = 1; d < 256; d <<= 1) {
        int t = (threadIdx.x >= (unsigned)d) ? ts[threadIdx.x - d] : 0;
        __syncthreads();
        ts[threadIdx.x] += t;
        __syncthreads();
    }
    int run = ts[threadIdx.x] - s;
    if (threadIdx.x == 255) bsum[blockIdx.x] = ts[255];
#pragma unroll
    for (int j = 0; j < 8; ++j) {
        if (i0 + j < n) out[i0 + j] = run;
        run += vals[j];
    }
}

__global__ void scan_partials_k(int* __restrict__ bsum, int nb) {
    if (threadIdx.x == 0 && blockIdx.x == 0) {
        int run = 0;
        for (int i = 0; i < nb; ++i) { int t = bsum[i]; bsum[i] = run; run += t; }
    }
}

__global__ void scan_add_k(int* __restrict__ rp, const int* __restrict__ bsum,
                           int n, int E)
{
    int i = blockIdx.x * blockDim.x + threadIdx.x;
    if (i < n) rp[i] += bsum[i >> 11];
    if (i == 0) rp[n] = E;
}

__global__ __launch_bounds__(256) void bucket_scatter_k(
    const int* __restrict__ src, const int* __restrict__ dst,
    const int* __restrict__ Tsc, uint2* __restrict__ pairs, int E, int NB)
{
    __shared__ int cur[512];
    for (int b = threadIdx.x; b < NB; b += 256)
        cur[b] = Tsc[b * gridDim.x + blockIdx.x];
    __syncthreads();
    int per = (E + gridDim.x - 1) / gridDim.x;
    int s = blockIdx.x * per;
    int e = min(E, s + per);
    for (int i = s + threadIdx.x; i < e; i += 256) {
        int d = dst[i];
        int pos = atomicAdd(&cur[d >> 8], 1);
        pairs[pos] = make_uint2((unsigned)d, (unsigned)src[i]);
    }
}

__global__ __launch_bounds__(256) void bucket_csr_k(
    const uint2* __restrict__ pairs, const int* __restrict__ Tsc,
    int* __restrict__ row_ptr, float* __restrict__ dis,
    int* __restrict__ csr, int N, int E, int NB, int G)
{
    __shared__ int cnt[256];
    __shared__ int ts[256];
    __shared__ int cur[256];
    const int b = blockIdx.x;
    const int node0 = b << 8;
    const int e0 = Tsc[b * G];
    const int e1 = Tsc[(b + 1) * G];
    const int j = threadIdx.x;
    cnt[j] = 0;
    __syncthreads();
    for (int i = e0 + j; i < e1; i += 256)
        atomicAdd(&cnt[pairs[i].x & 255u], 1);
    __syncthreads();
    int c = cnt[j];
    ts[j] = c;
    __syncthreads();
    for (int d = 1; d < 256; d <<= 1) {
        int t = (j >= d) ? ts[j - d] : 0;
        __syncthreads();
        ts[j] += t;
        __syncthreads();
    }
    int excl = ts[j] - c;
    int node = node0 + j;
    if (node < N) {
        row_ptr[node] = e0 + excl;
        dis[node] = rsqrtf(1.0f + (float)c);
    }
    cur[j] = e0 + excl;
    if (b == NB - 1 && j == 0) row_ptr[N] = E;
    __syncthreads();
    for (int i = e0 + j; i < e1; i += 256) {
        uint2 p = pairs[i];
        int pos = atomicAdd(&cur[p.x & 255u], 1);
        csr[pos] = (int)p.y;
    }
}

// ---------------- W fragment prebuild (once per layer) ----------------
// wfrag[((nn*NKK+kk)*64+lane)*8+e] = bf16(W[k][col]), col=nn*16+(lane&15),
// k=kk*32+(lane>>4)*8+e, zero-padded. Exact MFMA b-frag layout.

template<int FIN, int FOUT, int NKK, int CT>
__global__ void wfrag_build_k(const float* __restrict__ W,
                              __hip_bfloat16* __restrict__ out)
{
    int idx = blockIdx.x * 256 + threadIdx.x;
    if (idx >= CT * NKK * 64 * 8) return;
    int e = idx & 7;
    int lane = (idx >> 3) & 63;
    int t = idx >> 9;           // nn*NKK + kk
    int kk = t % NKK, nn = t / NKK;
    int col = nn * 16 + (lane & 15);
    int k = kk * 32 + (lane >> 4) * 8 + e;
    float v = (k < FIN && col < FOUT) ? W[k * FOUT + col] : 0.f;
    out[idx] = __float2bfloat16(v);
}

// ---------------- GEMM v5: MFMA, no LDS, no syncs ----------------
// a-frag: direct global load of in[row][k0..k0+8) -> bf16; b-frag: direct
// 16B load from prebuilt wfrag (L1-hot). D: col=l&15 -> W col, row=(l>>4)*4+i.

template<int FIN>
__device__ inline bf16x8 load_a8(const float* __restrict__ p, int k0) {
    bf16x8 r;
    if (k0 + 8 <= FIN) {
        float4 v0 = *reinterpret_cast<const float4*>(p + k0);
        float4 v1 = *reinterpret_cast<const float4*>(p + k0 + 4);
        r[0] = f2bf(v0.x); r[1] = f2bf(v0.y); r[2] = f2bf(v0.z); r[3] = f2bf(v0.w);
        r[4] = f2bf(v1.x); r[5] = f2bf(v1.y); r[6] = f2bf(v1.z); r[7] = f2bf(v1.w);
    } else {
#pragma unroll
        for (int e = 0; e < 8; ++e)
            r[e] = (k0 + e < FIN) ? f2bf(p[k0 + e]) : (short)0;
    }
    return r;
}

template<int FIN, int FOUT, int NKK, int CT>
__global__ __launch_bounds__(256) void gemm_mfma_v5(
    const float* __restrict__ in, const __hip_bfloat16* __restrict__ wfrag,
    const float* __restrict__ dis, __hip_bfloat16* __restrict__ hh, int n)
{
    const int tid = threadIdx.x;
    const long long base = (long long)blockIdx.x * 64;
    const int cnt = (int)min((long long)64, (long long)n - base);
    const int wv = tid >> 6, lane = tid & 63;
    const int rlo = lane & 15, kg = lane >> 4, kb = kg * 8;
    const int arow = wv * 16 + rlo;
    const long long row = base + arow;

    bf16x8 a[NKK];
    if (arow < cnt) {
        const float* p = &in[(size_t)row * FIN];
#pragma unroll
        for (int kk = 0; kk < NKK; ++kk)
            a[kk] = load_a8<FIN>(p, kk * 32 + kb);
    } else {
#pragma unroll
        for (int kk = 0; kk < NKK; ++kk)
            a[kk] = (bf16x8){0, 0, 0, 0, 0, 0, 0, 0};
    }

    f32x4 acc[CT];
#pragma unroll
    for (int nn = 0; nn < CT; ++nn) acc[nn] = (f32x4){0.f, 0.f, 0.f, 0.f};

#pragma unroll
    for (int nn = 0; nn < CT; ++nn) {
#pragma unroll
        for (int kk = 0; kk < NKK; ++kk) {
            bf16x8 b = *reinterpret_cast<const bf16x8*>(
                &wfrag[(size_t)((nn * NKK + kk) * 64 + lane) * 8]);
            acc[nn] = __builtin_amdgcn_mfma_f32_16x16x32_bf16(a[kk], b, acc[nn], 0, 0, 0);
        }
    }

    // epilogue: scale by dis, bf16 store (D: row=(l>>4)*4+i, col=nn*16+(l&15))
    const int r0 = wv * 16 + kg * 4;
    float dv[4];
#pragma unroll
    for (int i = 0; i < 4; ++i)
        dv[i] = (r0 + i < cnt) ? dis[base + r0 + i] : 0.f;
#pragma unroll
    for (int nn = 0; nn < CT; ++nn) {
        const int col = nn * 16 + rlo;
        if (col < FOUT) {
#pragma unroll
            for (int i = 0; i < 4; ++i) {
                int r = r0 + i;
                if (r < cnt) {
                    __hip_bfloat16 o = __float2bfloat16(acc[nn][i] * dv[i]);
                    hh[(size_t)(base + r) * FOUT + col] = o;
                }
            }
        }
    }
}

// ---------------- CSR aggregate v3: uint2 gathers, 8-deep MLP ----------------

template<int F>
__global__ __launch_bounds__(256) void aggregate_v3(
    const __hip_bfloat16* __restrict__ hh, const int* __restrict__ row_ptr,
    const int* __restrict__ csr, const float* __restrict__ dis,
    const float* __restrict__ b, float* __restrict__ out, int n)
{
    constexpr int FG = F / 4;
    long long idx = (long long)blockIdx.x * 256 + threadIdx.x;
    if (idx >= (long long)n * FG) return;
    int node = (int)(idx / FG);
    int fg = (int)(idx - (long long)node * FG);
    const int bf = fg * 4;

    const unsigned short* hs = (const unsigned short*)hh;
    auto lo16 = [](unsigned u) { return __uint_as_float(u << 16); };
    auto hi16 = [](unsigned u) { return __uint_as_float(u & 0xFFFF0000u); };

    uint2 su = *reinterpret_cast<const uint2*>(&hs[(size_t)node * F + bf]);
    float a0 = lo16(su.x), a1 = hi16(su.x), a2 = lo16(su.y), a3 = hi16(su.y);
    float c0 = 0.f, c1 = 0.f, c2 = 0.f, c3 = 0.f;

    int e = row_ptr[node];
    const int e1 = row_ptr[node + 1];
    for (; e + 8 <= e1; e += 8) {
        int s0 = csr[e],     s1 = csr[e + 1], s2 = csr[e + 2], s3 = csr[e + 3];
        int s4 = csr[e + 4], s5 = csr[e + 5], s6 = csr[e + 6], s7 = csr[e + 7];
        uint2 u0 = *reinterpret_cast<const uint2*>(&hs[(size_t)s0 * F + bf]);
        uint2 u1 = *reinterpret_cast<const uint2*>(&hs[(size_t)s1 * F + bf]);
        uint2 u2 = *reinterpret_cast<const uint2*>(&hs[(size_t)s2 * F + bf]);
        uint2 u3 = *reinterpret_cast<const uint2*>(&hs[(size_t)s3 * F + bf]);
        uint2 u4 = *reinterpret_cast<const uint2*>(&hs[(size_t)s4 * F + bf]);
        uint2 u5 = *reinterpret_cast<const uint2*>(&hs[(size_t)s5 * F + bf]);
        uint2 u6 = *reinterpret_cast<const uint2*>(&hs[(size_t)s6 * F + bf]);
        uint2 u7 = *reinterpret_cast<const uint2*>(&hs[(size_t)s7 * F + bf]);
        a0 += lo16(u0.x); a1 += hi16(u0.x); a2 += lo16(u0.y); a3 += hi16(u0.y);
        c0 += lo16(u1.x); c1 += hi16(u1.x); c2 += lo16(u1.y); c3 += hi16(u1.y);
        a0 += lo16(u2.x); a1 += hi16(u2.x); a2 += lo16(u2.y); a3 += hi16(u2.y);
        c0 += lo16(u3.x); c1 += hi16(u3.x); c2 += lo16(u3.y); c3 += hi16(u3.y);
        a0 += lo16(u4.x); a1 += hi16(u4.x); a2 += lo16(u4.y); a3 += hi16(u4.y);
        c0 += lo16(u5.x); c1 += hi16(u5.x); c2 += lo16(u5.y); c3 += hi16(u5.y);
        a0 += lo16(u6.x); a1 += hi16(u6.x); a2 += lo16(u6.y); a3 += hi16(u6.y);
        c0 += lo16(u7.x); c1 += hi16(u7.x); c2 += lo16(u7.y); c3 += hi16(u7.y);
    }
    if (e + 4 <= e1) {
        int s0 = csr[e], s1 = csr[e + 1], s2 = csr[e + 2], s3 = csr[e + 3];
        uint2 u0 = *reinterpret_cast<const uint2*>(&hs[(size_t)s0 * F + bf]);
        uint2 u1 = *reinterpret_cast<const uint2*>(&hs[(size_t)s1 * F + bf]);
        uint2 u2 = *reinterpret_cast<const uint2*>(&hs[(size_t)s2 * F + bf]);
        uint2 u3 = *reinterpret_cast<const uint2*>(&hs[(size_t)s3 * F + bf]);
        a0 += lo16(u0.x); a1 += hi16(u0.x); a2 += lo16(u0.y); a3 += hi16(u0.y);
        c0 += lo16(u1.x); c1 += hi16(u1.x); c2 += lo16(u1.y); c3 += hi16(u1.y);
        a0 += lo16(u2.x); a1 += hi16(u2.x); a2 += lo16(u2.y); a3 += hi16(u2.y);
        c0 += lo16(u3.x); c1 += hi16(u3.x); c2 += lo16(u3.y); c3 += hi16(u3.y);
        e += 4;
    }
    for (; e < e1; ++e) {
        int s = csr[e];
        uint2 u = *reinterpret_cast<const uint2*>(&hs[(size_t)s * F + bf]);
        a0 += lo16(u.x); a1 += hi16(u.x); a2 += lo16(u.y); a3 += hi16(u.y);
    }
    a0 += c0; a1 += c1; a2 += c2; a3 += c3;

    float d = dis[node];
    float4 bb = *reinterpret_cast<const float4*>(&b[bf]);
    float4 o;
    o.x = fmaxf(fmaf(d, a0, bb.x), 0.0f);
    o.y = fmaxf(fmaf(d, a1, bb.y), 0.0f);
    o.z = fmaxf(fmaf(d, a2, bb.z), 0.0f);
    o.w = fmaxf(fmaf(d, a3, bb.w), 0.0f);
    *reinterpret_cast<float4*>(&out[(size_t)node * F + bf]) = o;
}

// ---------------- pooling ----------------

__global__ __launch_bounds__(256) void pool2_k(
    const float* __restrict__ h, const int* __restrict__ batch,
    float* __restrict__ sums, float* __restrict__ cnt, int n)
{
    constexpr int CHUNK = 1024;
    __shared__ float s[64 * 32];
    __shared__ float sc[64];
    for (int i = threadIdx.x; i < 64 * 32; i += 256) s[i] = 0.0f;
    if (threadIdx.x < 64) sc[threadIdx.x] = 0.0f;
    __syncthreads();

    long long start = (long long)blockIdx.x * CHUNK;
    long long end = start + CHUNK < n ? start + CHUNK : n;
    int total = (int)(end - start) * 32;
    for (int i = threadIdx.x; i < total; i += 256) {
        int r = i >> 5;
        int f = i & 31;
        int node = (int)start + r;
        int g = batch[node];
        atomicAdd(&s[g * 32 + f], h[(size_t)node * 32 + f]);
        if (f == 0) atomicAdd(&sc[g], 1.0f);
    }
    __syncthreads();
    for (int i = threadIdx.x; i < 64 * 32; i += 256) {
        float v = s[i];
        if (v != 0.0f) atomicAdd(&sums[i], v);
    }
    if (threadIdx.x < 64) {
        float v = sc[threadIdx.x];
        if (v != 0.0f) atomicAdd(&cnt[threadIdx.x], v);
    }
}

__global__ void head_k(const float* __restrict__ sums, const float* __restrict__ cnt,
                       const float* __restrict__ Wl, const float* __restrict__ bl,
                       float* __restrict__ out)
{
    int tid = threadIdx.x;
    if (tid < 128) {
        int g = tid >> 1;
        int o = tid & 1;
        float c = fmaxf(cnt[g], 1.0f);
        float a = 0.0f;
#pragma unroll
        for (int f = 0; f < 32; ++f)
            a += (sums[g * 32 + f] / c) * Wl[f * 2 + o];
        out[tid] = a + bl[o];
    }
}

// ---------------- launch ----------------

extern "C" void kernel_launch(void* const* d_in, const int* in_sizes, int n_in,
                              void* d_out, int out_size, void* d_ws, size_t ws_size,
                              hipStream_t stream)
{
    const float* x   = (const float*)d_in[0];
    const int*   ei  = (const int*)d_in[1];
    const int*   bat = (const int*)d_in[2];
    const float* W1  = (const float*)d_in[3];
    const float* b1  = (const float*)d_in[4];
    const float* W2  = (const float*)d_in[5];
    const float* b2  = (const float*)d_in[6];
    const float* W3  = (const float*)d_in[7];
    const float* b3  = (const float*)d_in[8];
    const float* Wl  = (const float*)d_in[9];
    const float* bl  = (const float*)d_in[10];

    const int N = in_sizes[0] / 128;
    const int E = in_sizes[1] / 2;
    const int* src = ei;
    const int* dst = ei + E;

    const int NB = (N + 255) >> 8;
    const int G  = 128;
    const int NBG = NB * G;

    char* ws = (char*)d_ws;
    size_t off = 0;
    auto alloc = [&](size_t bytes) -> char* {
        char* p = ws + off;
        off += (bytes + 255) & ~(size_t)255;
        return p;
    };
    float* dis     = (float*)alloc((size_t)N * 4);
    int*   row_ptr = (int*)  alloc((size_t)(N + 1) * 4);
    int*   bsum    = (int*)  alloc(256 * 4);
    int*   csr     = (int*)  alloc((size_t)E * 4);
    int*   T       = (int*)  alloc((size_t)NBG * 4);
    int*   Tsc     = (int*)  alloc((size_t)(NBG + 1) * 4);
    __hip_bfloat16* WF1 = (__hip_bfloat16*)alloc(6 * 4 * 512 * 2);
    __hip_bfloat16* WF2 = (__hip_bfloat16*)alloc(4 * 3 * 512 * 2);
    __hip_bfloat16* WF3 = (__hip_bfloat16*)alloc(2 * 2 * 512 * 2);
    __hip_bfloat16* A = (__hip_bfloat16*)alloc((size_t)N * 84 * 2);
    float* B       = (float*)alloc((size_t)N * 84 * 4);
    float* C       = (float*)alloc((size_t)N * 64 * 4);
    float* D       = (float*)alloc((size_t)(64 * 32 + 64) * 4);
    uint2* pairs   = (uint2*)C;

    dim3 blk(256);
    auto cdiv = [](long long a, long long b) { return (int)((a + b - 1) / b); };

    // ---- W fragment prebuild ----
    wfrag_build_k<128, 84, 4, 6><<<cdiv(6 * 4 * 512, 256), blk, 0, stream>>>(W1, WF1);
    wfrag_build_k< 84, 64, 3, 4><<<cdiv(4 * 3 * 512, 256), blk, 0, stream>>>(W2, WF2);
    wfrag_build_k< 64, 32, 2, 2><<<cdiv(2 * 2 * 512, 256), blk, 0, stream>>>(W3, WF3);

    // ---- bucketed CSR build ----
    bucket_hist_k<<<G, blk, 0, stream>>>(dst, T, E, NB);
    int nb_scan = cdiv(NBG, 2048);
    scan_block_k<<<nb_scan, blk, 0, stream>>>(T, Tsc, bsum, NBG);
    scan_partials_k<<<1, 64, 0, stream>>>(bsum, nb_scan);
    scan_add_k<<<cdiv(NBG, 256), blk, 0, stream>>>(Tsc, bsum, NBG, E);
    bucket_scatter_k<<<G, blk, 0, stream>>>(src, dst, Tsc, pairs, E, NB);
    bucket_csr_k<<<NB, blk, 0, stream>>>(pairs, Tsc, row_ptr, dis, csr, N, E, NB, G);

    // Layer 1: 128 -> 84
    gemm_mfma_v5<128, 84, 4, 6><<<cdiv(N, 64), blk, 0, stream>>>(x, WF1, dis, A, N);
    aggregate_v3<84><<<cdiv((long long)N * 21, 256), blk, 0, stream>>>(A, row_ptr, csr, dis, b1, B, N);

    // Layer 2: 84 -> 64
    gemm_mfma_v5<84, 64, 3, 4><<<cdiv(N, 64), blk, 0, stream>>>(B, WF2, dis, A, N);
    aggregate_v3<64><<<cdiv((long long)N * 16, 256), blk, 0, stream>>>(A, row_ptr, csr, dis, b2, C, N);

    // Layer 3: 64 -> 32
    gemm_mfma_v5<64, 32, 2, 2><<<cdiv(N, 64), blk, 0, stream>>>(C, WF3, dis, A, N);
    aggregate_v3<32><<<cdiv((long long)N * 8, 256), blk, 0, stream>>>(A, row_ptr, csr, dis, b3, B, N);

    // global mean pool + head
    zero_k<<<cdiv(64 * 32 + 64, 256), blk, 0, stream>>>(D, 64 * 32 + 64);
    pool2_k<<<cdiv(N, 1024), blk, 0, stream>>>(B, bat, D, D + 64 * 32, N);
    head_k<<<1, 128, 0, stream>>>(D, D + 64 * 32, Wl, bl, (float*)d_out);
}